// Round 10
// baseline (233.077 us; speedup 1.0000x reference)
//
#include <hip/hip_runtime.h>
#include <hip/hip_fp16.h>
#include <math.h>

#define NB 8
#define NC 512
#define NN 2048

typedef __attribute__((ext_vector_type(8))) _Float16 f16x8;
typedef __attribute__((ext_vector_type(4))) float f32x4;
typedef __attribute__((ext_vector_type(16))) float f32x16;

union U8 { uint32_t u[4]; f16x8 v; };

__device__ __forceinline__ unsigned f2mono(float v) {
    unsigned b = __float_as_uint(v);
    return (b & 0x80000000u) ? ~b : (b | 0x80000000u);
}

__device__ __forceinline__ uint32_t packsplit(float a) {
    __half h = __float2half(a);
    float hf = __half2float(h);
    __half lo = __float2half(a - hf);
    return (uint32_t)__half_as_ushort(h) | ((uint32_t)__half_as_ushort(lo) << 16);
}

__device__ __forceinline__ void g2lds16(const void* g, void* l) {
    __builtin_amdgcn_global_load_lds(
        (const __attribute__((address_space(1))) void*)g,
        (__attribute__((address_space(3))) void*)l, 16, 0, 0);
}

// ---------- Kernel P: f32 [b][k][n] -> hi/lo fp16 planes [b][n][k], octet-swizzled ----------
extern "C" __global__ __launch_bounds__(256)
void prepack(const float* __restrict__ srcE, const float* __restrict__ tgtE,
             unsigned short* __restrict__ hiA, unsigned short* __restrict__ loA,
             unsigned short* __restrict__ hiB, unsigned short* __restrict__ loB)
{
    const float* in = blockIdx.y ? tgtE : srcE;
    unsigned short* hi = blockIdx.y ? hiB : hiA;
    unsigned short* lo = blockIdx.y ? loB : loA;
    const int t  = blockIdx.x;          // 1024 tiles: 8 b x 16 kt x 8 nt
    const int b  = t >> 7;
    const int kt = (t >> 3) & 15;
    const int nt = t & 7;
    const int k0 = kt * 32, n0 = nt * 256;

    const int n_l = threadIdx.x;
    const int n   = n0 + n_l;
    const int s2  = (n >> 1) & 3;
    const float* gin = in + (size_t)b * (NC * NN) + (size_t)k0 * NN + n;

    float v[32];
#pragma unroll
    for (int k = 0; k < 32; ++k) v[k] = gin[(size_t)k * NN];

    uint32_t hw[16], lw[16];
#pragma unroll
    for (int j = 0; j < 16; ++j) {
        __half h0 = __float2half(v[2*j]);
        __half h1 = __float2half(v[2*j+1]);
        float  d0 = v[2*j]   - __half2float(h0);
        float  d1 = v[2*j+1] - __half2float(h1);
        hw[j] = (uint32_t)__half_as_ushort(h0) | ((uint32_t)__half_as_ushort(h1) << 16);
        lw[j] = (uint32_t)__half_as_ushort(__float2half(d0)) |
                ((uint32_t)__half_as_ushort(__float2half(d1)) << 16);
    }
    const size_t rowbase = ((size_t)b * NN + n) * NC;
#pragma unroll
    for (int o = 0; o < 4; ++o) {
        const int P = kt * 4 + (o ^ s2);
        uint4 qh, ql;
        qh.x = hw[4*o+0]; qh.y = hw[4*o+1]; qh.z = hw[4*o+2]; qh.w = hw[4*o+3];
        ql.x = lw[4*o+0]; ql.y = lw[4*o+1]; ql.z = lw[4*o+2]; ql.w = lw[4*o+3];
        *(uint4*)(hi + rowbase + (size_t)P * 8) = qh;
        *(uint4*)(lo + rowbase + (size_t)P * 8) = ql;
    }
}

// ---------- Kernel G: 128x128 tile, 4 waves, single 32KB LDS buffer, 32x32x16 MFMA ----------
// planes: 0=A-hi 1=A-lo 2=B-hi 3=B-lo ; [4 plane][128 rows x 32 k] u16 = 32KB -> 3+ blocks/CU
// A frag (32x32x16): row = lane&31, k = (lane>>5)*8 + j  (contiguous-octet pattern, HW-verified
// for the 16x16x32 analog). C/D: col = lane&31 (m), row = (reg&3)+8*(reg>>2)+4*(lane>>5) (n).
extern "C" __global__ __launch_bounds__(256, 2)
void scores_argmax_32(const unsigned short* __restrict__ hiA, const unsigned short* __restrict__ loA,
                      const unsigned short* __restrict__ hiB, const unsigned short* __restrict__ loB,
                      const float* __restrict__ gum,
                      unsigned long long* __restrict__ best)
{
    __shared__ unsigned short lds[4][4096];

    const int id = blockIdx.x;
    const int flat = (id & 7) * 256 + (id >> 3);  // XCD swizzle (2048 % 8 == 0, bijective)
    const int mt = flat & 15;
    const int nt = (flat >> 4) & 15;
    const int b  = flat >> 8;
    const int n0 = nt * 128, m0 = mt * 128;

    const int tid = threadIdx.x;
    const int wv = tid >> 6;
    const int l  = tid & 63;
    const int wn = wv >> 1, wm = wv & 1;     // wave tile: 64x64 = 2x2 of 32x32
    const int c32 = l & 31, half = l >> 5;
    const int s2 = (c32 >> 1) & 3;           // prepack swizzle key (row mod 32 basis)

    // staging: wave wv stages plane wv (verified R5/R9 map)
    const unsigned short* gp;
    int pan;
    if (wv == 0)      { gp = hiA; pan = n0; }
    else if (wv == 1) { gp = loA; pan = n0; }
    else if (wv == 2) { gp = hiB; pan = m0; }
    else              { gp = loB; pan = m0; }
    gp += ((size_t)b * NN + pan) * NC;
    const unsigned short* gl = gp + (size_t)(l >> 2) * NC + (l & 3) * 8;  // + t*32 per K-tile

    f32x16 acc[2][2];
#pragma unroll
    for (int i = 0; i < 2; ++i)
#pragma unroll
        for (int j = 0; j < 2; ++j)
#pragma unroll
            for (int r = 0; r < 16; ++r)
                acc[i][j][r] = 0.f;

#pragma unroll 1
    for (int t = 0; t < 16; ++t) {
        __syncthreads();                    // readers of previous tile done
        {
            const unsigned short* s_ = gl + (size_t)t * 32;
#pragma unroll
            for (int c = 0; c < 8; ++c)
                g2lds16(s_ + (size_t)c * 16 * NC, &lds[wv][c * 512]);
        }
        __syncthreads();                    // compiler drains vmcnt before barrier -> tile ready

#pragma unroll
        for (int kin = 0; kin < 2; ++kin) {
            const int fo = (((kin * 2 + half) ^ s2)) * 8;   // octet slot (u16 units)
            f16x8 bh[2], bl[2];
#pragma unroll
            for (int ms = 0; ms < 2; ++ms) {
                const int rB = wm * 64 + ms * 32 + c32;
                bh[ms] = *(const f16x8*)&lds[2][rB * 32 + fo];
                bl[ms] = *(const f16x8*)&lds[3][rB * 32 + fo];
            }
#pragma unroll
            for (int ns = 0; ns < 2; ++ns) {
                const int rA = wn * 64 + ns * 32 + c32;
                const f16x8 ah = *(const f16x8*)&lds[0][rA * 32 + fo];
                const f16x8 al = *(const f16x8*)&lds[1][rA * 32 + fo];
#pragma unroll
                for (int ms = 0; ms < 2; ++ms) {
                    acc[ns][ms] = __builtin_amdgcn_mfma_f32_32x32x16_f16(ah, bh[ms], acc[ns][ms], 0, 0, 0);
                    acc[ns][ms] = __builtin_amdgcn_mfma_f32_32x32x16_f16(al, bh[ms], acc[ns][ms], 0, 0, 0);
                    acc[ns][ms] = __builtin_amdgcn_mfma_f32_32x32x16_f16(ah, bl[ms], acc[ns][ms], 0, 0, 0);
                }
            }
        }
    }

    // ---- fused gumbel + per-row argmax (fast log; /tau dropped: argmax-invariant, tau>0) ----
    const float SCL = 0.044194173824159216f;  // 1/sqrt(512)
#pragma unroll
    for (int ns = 0; ns < 2; ++ns) {
#pragma unroll
        for (int reg = 0; reg < 16; ++reg) {
            const int n = n0 + wn * 64 + ns * 32 + (reg & 3) + 8 * (reg >> 2) + 4 * half;
            const float* gr = gum + ((size_t)(b * NN + n)) * NN + m0 + wm * 64 + c32;
            unsigned long long bp = 0ULL;
#pragma unroll
            for (int ms = 0; ms < 2; ++ms) {
                float u = gr[ms * 32];
                u = fminf(fmaxf(u, 1e-6f), 1.0f - 1e-6f);
                const float g = -__logf(-__logf(u));
                const float val = fmaf(acc[ns][ms][reg], SCL, g);
                const int m = m0 + wm * 64 + ms * 32 + c32;
                const unsigned long long p =
                    ((unsigned long long)f2mono(val) << 32) | (unsigned)(NN - 1 - m);
                if (p > bp) bp = p;
            }
#pragma unroll
            for (int off = 16; off > 0; off >>= 1) {
                const unsigned long long o = __shfl_xor(bp, off, 32);
                if (o > bp) bp = o;
            }
            if (c32 == 0) atomicMax(&best[(size_t)b * NN + n], bp);
        }
    }
}

// ---------- Fallback (R3 kernel, proven): used only if ws too small ----------
extern "C" __global__ __launch_bounds__(256, 2)
void scores_argmax(const float* __restrict__ srcE,
                   const float* __restrict__ tgtE,
                   const float* __restrict__ gum,
                   const float* __restrict__ temp,
                   unsigned long long* __restrict__ best)
{
    __shared__ uint32_t As[128 * 32];
    __shared__ uint32_t Bs[128 * 32];
    const int id = blockIdx.x;
    const int flat = (id & 7) * 256 + (id >> 3);
    const int mt = flat & 15;
    const int nt = (flat >> 4) & 15;
    const int b  = flat >> 8;
    const int n0 = nt * 128, m0 = mt * 128;

    const int tid = threadIdx.x;
    const int wv = tid >> 6;
    const int l  = tid & 63;
    const int wn = wv >> 1, wm = wv & 1;
    const int row16 = l & 15, h = l >> 4;

    const int snb = 4 * (tid & 31);
    const int skb = tid >> 5;
    const uint32_t sswz = (uint32_t)(tid & 7) << 2;

    const float* Ag = srcE + (size_t)b * NC * NN + n0 + snb;
    const float* Bg = tgtE + (size_t)b * NC * NN + m0 + snb;

    float4 pA[4], pB[4];
#pragma unroll
    for (int r = 0; r < 4; ++r) {
        pA[r] = *(const float4*)(Ag + (size_t)(skb + 8 * r) * NN);
        pB[r] = *(const float4*)(Bg + (size_t)(skb + 8 * r) * NN);
    }

    f32x4 acc[4][4];
#pragma unroll
    for (int i = 0; i < 4; ++i)
#pragma unroll
        for (int j = 0; j < 4; ++j)
            acc[i][j] = (f32x4){0.f, 0.f, 0.f, 0.f};

    for (int k0 = 0; k0 < NC; k0 += 32) {
        __syncthreads();
#pragma unroll
        for (int r = 0; r < 4; ++r) {
            const int k = skb + 8 * r;
            const uint32_t kx = (uint32_t)k ^ sswz;
            uint32_t* ap = &As[snb * 32 + kx];
            uint32_t* bq = &Bs[snb * 32 + kx];
            ap[0]  = packsplit(pA[r].x); ap[32] = packsplit(pA[r].y);
            ap[64] = packsplit(pA[r].z); ap[96] = packsplit(pA[r].w);
            bq[0]  = packsplit(pB[r].x); bq[32] = packsplit(pB[r].y);
            bq[64] = packsplit(pB[r].z); bq[96] = packsplit(pB[r].w);
        }
        if (k0 + 32 < NC) {
#pragma unroll
            for (int r = 0; r < 4; ++r) {
                pA[r] = *(const float4*)(Ag + (size_t)(k0 + 32 + skb + 8 * r) * NN);
                pB[r] = *(const float4*)(Bg + (size_t)(k0 + 32 + skb + 8 * r) * NN);
            }
        }
        __syncthreads();

        U8 bfh[4], bfl[4];
#pragma unroll
        for (int ms = 0; ms < 4; ++ms) {
            const int m_loc = wm * 64 + ms * 16 + row16;
            const uint32_t swz = (uint32_t)((ms * 4 + (row16 >> 2)) & 7) << 2;
            const int base = m_loc * 32;
            const uint4 r0 = *(const uint4*)&Bs[base + (((uint32_t)(h * 8 + 0)) ^ swz)];
            const uint4 r1 = *(const uint4*)&Bs[base + (((uint32_t)(h * 8 + 4)) ^ swz)];
            bfh[ms].u[0] = __builtin_amdgcn_perm(r0.y, r0.x, 0x05040100u);
            bfh[ms].u[1] = __builtin_amdgcn_perm(r0.w, r0.z, 0x05040100u);
            bfh[ms].u[2] = __builtin_amdgcn_perm(r1.y, r1.x, 0x05040100u);
            bfh[ms].u[3] = __builtin_amdgcn_perm(r1.w, r1.z, 0x05040100u);
            bfl[ms].u[0] = __builtin_amdgcn_perm(r0.y, r0.x, 0x07060302u);
            bfl[ms].u[1] = __builtin_amdgcn_perm(r0.w, r0.z, 0x07060302u);
            bfl[ms].u[2] = __builtin_amdgcn_perm(r1.y, r1.x, 0x07060302u);
            bfl[ms].u[3] = __builtin_amdgcn_perm(r1.w, r1.z, 0x07060302u);
        }

#pragma unroll
        for (int ns = 0; ns < 4; ++ns) {
            const int n_loc = wn * 64 + ns * 16 + row16;
            const uint32_t swz = (uint32_t)((ns * 4 + (row16 >> 2)) & 7) << 2;
            const int base = n_loc * 32;
            const uint4 r0 = *(const uint4*)&As[base + (((uint32_t)(h * 8 + 0)) ^ swz)];
            const uint4 r1 = *(const uint4*)&As[base + (((uint32_t)(h * 8 + 4)) ^ swz)];
            U8 ah, al;
            ah.u[0] = __builtin_amdgcn_perm(r0.y, r0.x, 0x05040100u);
            ah.u[1] = __builtin_amdgcn_perm(r0.w, r0.z, 0x05040100u);
            ah.u[2] = __builtin_amdgcn_perm(r1.y, r1.x, 0x05040100u);
            ah.u[3] = __builtin_amdgcn_perm(r1.w, r1.z, 0x05040100u);
            al.u[0] = __builtin_amdgcn_perm(r0.y, r0.x, 0x07060302u);
            al.u[1] = __builtin_amdgcn_perm(r0.w, r0.z, 0x07060302u);
            al.u[2] = __builtin_amdgcn_perm(r1.y, r1.x, 0x07060302u);
            al.u[3] = __builtin_amdgcn_perm(r1.w, r1.z, 0x07060302u);
#pragma unroll
            for (int ms = 0; ms < 4; ++ms) {
                acc[ns][ms] = __builtin_amdgcn_mfma_f32_16x16x32_f16(ah.v, bfh[ms].v, acc[ns][ms], 0, 0, 0);
                acc[ns][ms] = __builtin_amdgcn_mfma_f32_16x16x32_f16(al.v, bfh[ms].v, acc[ns][ms], 0, 0, 0);
                acc[ns][ms] = __builtin_amdgcn_mfma_f32_16x16x32_f16(ah.v, bfl[ms].v, acc[ns][ms], 0, 0, 0);
            }
        }
    }

    const float SCL = 0.044194173824159216f;
    const float tau = temp[b];
#pragma unroll
    for (int ns = 0; ns < 4; ++ns) {
#pragma unroll
        for (int reg = 0; reg < 4; ++reg) {
            const int n = n0 + wn * 64 + ns * 16 + h * 4 + reg;
            const float* gr = gum + ((size_t)(b * NN + n)) * NN + m0 + wm * 64 + row16;
            unsigned long long bp = 0ULL;
#pragma unroll
            for (int ms = 0; ms < 4; ++ms) {
                float u = gr[ms * 16];
                u = fminf(fmaxf(u, 1e-6f), 1.0f - 1e-6f);
                const float g = -logf(-logf(u));
                const float val = (acc[ns][ms][reg] * SCL + g) / tau;
                const int m = m0 + wm * 64 + ms * 16 + row16;
                const unsigned long long p =
                    ((unsigned long long)f2mono(val) << 32) | (unsigned)(NN - 1 - m);
                if (p > bp) bp = p;
            }
#pragma unroll
            for (int off = 8; off > 0; off >>= 1) {
                const unsigned long long o = __shfl_xor(bp, off, 16);
                if (o > bp) bp = o;
            }
            if (row16 == 0) atomicMax(&best[(size_t)b * NN + n], bp);
        }
    }
}

// ---------- Kernel 2: gather + covariance + 3x3 SVD + R,t ----------
__device__ __forceinline__ double det3(const double M[3][3]) {
    return M[0][0] * (M[1][1] * M[2][2] - M[1][2] * M[2][1])
         - M[0][1] * (M[1][0] * M[2][2] - M[1][2] * M[2][0])
         + M[0][2] * (M[1][0] * M[2][1] - M[1][1] * M[2][0]);
}

extern "C" __global__ __launch_bounds__(1024)
void assemble(const float* __restrict__ src, const float* __restrict__ tgt,
              const unsigned long long* __restrict__ best, float* __restrict__ out)
{
    const int b = blockIdx.x;
    const int tid = threadIdx.x;
    float P[9] = {}, Ss[3] = {}, Sc[3] = {};
    for (int n = tid; n < NN; n += 1024) {
        const int m = (NN - 1) - (int)(unsigned)(best[(size_t)b * NN + n] & 0xffffffffu);
        float sv[3], cv[3];
#pragma unroll
        for (int c = 0; c < 3; ++c) {
            sv[c] = src[((size_t)b * 3 + c) * NN + n];
            cv[c] = tgt[((size_t)b * 3 + c) * NN + m];
            Ss[c] += sv[c];
            Sc[c] += cv[c];
        }
#pragma unroll
        for (int c = 0; c < 3; ++c)
#pragma unroll
            for (int d = 0; d < 3; ++d)
                P[c * 3 + d] = fmaf(sv[c], cv[d], P[c * 3 + d]);
    }

    float vals[15];
#pragma unroll
    for (int i = 0; i < 9; ++i) vals[i] = P[i];
#pragma unroll
    for (int i = 0; i < 3; ++i) { vals[9 + i] = Ss[i]; vals[12 + i] = Sc[i]; }

    __shared__ float red[16][15];
    const int lane = tid & 63, wv = tid >> 6;
#pragma unroll
    for (int i = 0; i < 15; ++i) {
        float v = vals[i];
        for (int off = 32; off > 0; off >>= 1) v += __shfl_down(v, off, 64);
        if (lane == 0) red[wv][i] = v;
    }
    __syncthreads();

    if (tid == 0) {
        double tot[15];
        for (int i = 0; i < 15; ++i) {
            double s = 0.0;
            for (int wq = 0; wq < 16; ++wq) s += (double)red[wq][i];
            tot[i] = s;
        }
        double smean[3], cmean[3], H[3][3];
        for (int c = 0; c < 3; ++c) { smean[c] = tot[9 + c] / NN; cmean[c] = tot[12 + c] / NN; }
        for (int c = 0; c < 3; ++c)
            for (int d = 0; d < 3; ++d)
                H[c][d] = tot[c * 3 + d] - tot[9 + c] * tot[12 + d] / NN;

        double W[3][3], V[3][3];
        for (int i = 0; i < 3; ++i)
            for (int j = 0; j < 3; ++j) { W[i][j] = H[i][j]; V[i][j] = (i == j) ? 1.0 : 0.0; }
        for (int sweep = 0; sweep < 60; ++sweep) {
            double offsum = 0.0;
            for (int p = 0; p < 2; ++p)
                for (int q = p + 1; q < 3; ++q) {
                    double al = 0, be = 0, ga = 0;
                    for (int r = 0; r < 3; ++r) {
                        al += W[r][p] * W[r][p];
                        be += W[r][q] * W[r][q];
                        ga += W[r][p] * W[r][q];
                    }
                    offsum += fabs(ga);
                    if (fabs(ga) <= 1e-15 * sqrt(al * be)) continue;
                    double zeta = (be - al) / (2.0 * ga);
                    double t = copysign(1.0, zeta) / (fabs(zeta) + sqrt(1.0 + zeta * zeta));
                    double c = 1.0 / sqrt(1.0 + t * t), s = c * t;
                    for (int r = 0; r < 3; ++r) {
                        double wp = W[r][p], wq = W[r][q];
                        W[r][p] = c * wp - s * wq;
                        W[r][q] = s * wp + c * wq;
                        double vp = V[r][p], vq = V[r][q];
                        V[r][p] = c * vp - s * vq;
                        V[r][q] = s * vp + c * vq;
                    }
                }
            if (offsum < 1e-13) break;
        }
        double S[3];
        for (int i = 0; i < 3; ++i)
            S[i] = sqrt(W[0][i] * W[0][i] + W[1][i] * W[1][i] + W[2][i] * W[2][i]);
        for (int i = 0; i < 2; ++i) {
            int mx = i;
            for (int j = i + 1; j < 3; ++j) if (S[j] > S[mx]) mx = j;
            if (mx != i) {
                double tS = S[i]; S[i] = S[mx]; S[mx] = tS;
                for (int r = 0; r < 3; ++r) {
                    double tw = W[r][i]; W[r][i] = W[r][mx]; W[r][mx] = tw;
                    double tv = V[r][i]; V[r][i] = V[r][mx]; V[r][mx] = tv;
                }
            }
        }
        double U[3][3];
        for (int i = 0; i < 3; ++i) {
            if (S[i] > 1e-12 * S[0] && S[i] > 0.0) {
                for (int r = 0; r < 3; ++r) U[r][i] = W[r][i] / S[i];
            } else {
                double ux = U[1][0] * U[2][1] - U[2][0] * U[1][1];
                double uy = U[2][0] * U[0][1] - U[0][0] * U[2][1];
                double uz = U[0][0] * U[1][1] - U[1][0] * U[0][1];
                double nr = sqrt(ux * ux + uy * uy + uz * uz);
                if (nr < 1e-30) { ux = 1.0; uy = 0.0; uz = 0.0; nr = 1.0; }
                U[0][i] = ux / nr; U[1][i] = uy / nr; U[2][i] = uz / nr;
            }
        }
        double r_[3][3];
        for (int i = 0; i < 3; ++i)
            for (int j = 0; j < 3; ++j)
                r_[i][j] = V[i][0] * U[j][0] + V[i][1] * U[j][1] + V[i][2] * U[j][2];
        double det = det3(r_);
        double R[3][3];
        for (int i = 0; i < 3; ++i)
            for (int j = 0; j < 3; ++j)
                R[i][j] = V[i][0] * U[j][0] + V[i][1] * U[j][1] + det * V[i][2] * U[j][2];
        double t_[3];
        for (int i = 0; i < 3; ++i)
            t_[i] = -(R[i][0] * smean[0] + R[i][1] * smean[1] + R[i][2] * smean[2]) + cmean[i];

        for (int i = 0; i < 3; ++i)
            for (int j = 0; j < 3; ++j)
                out[b * 9 + i * 3 + j] = (float)R[i][j];
        for (int i = 0; i < 3; ++i) out[NB * 9 + b * 3 + i] = (float)t_[i];
    }
}

// ---------- launcher ----------
extern "C" void kernel_launch(void* const* d_in, const int* in_sizes, int n_in,
                              void* d_out, int out_size, void* d_ws, size_t ws_size,
                              hipStream_t stream)
{
    const float* srcE = (const float*)d_in[0];
    const float* tgtE = (const float*)d_in[1];
    const float* src  = (const float*)d_in[2];
    const float* tgt  = (const float*)d_in[3];
    const float* temp = (const float*)d_in[4];
    const float* gum  = (const float*)d_in[5];
    float* out = (float*)d_out;
    unsigned long long* best = (unsigned long long*)d_ws;

    (void)hipMemsetAsync(best, 0, (size_t)NB * NN * sizeof(unsigned long long), stream);

    const size_t PLANE = (size_t)NB * NN * NC;                 // u16 elements per plane
    const size_t NEED  = 131072 + 4 * PLANE * sizeof(unsigned short);  // 128KB + 64MB
    if (ws_size >= NEED) {
        unsigned short* hiA = (unsigned short*)((char*)d_ws + 131072);
        unsigned short* loA = hiA + PLANE;
        unsigned short* hiB = loA + PLANE;
        unsigned short* loB = hiB + PLANE;
        prepack<<<dim3(1024, 2), 256, 0, stream>>>(srcE, tgtE, hiA, loA, hiB, loB);
        scores_argmax_32<<<2048, 256, 0, stream>>>(hiA, loA, hiB, loB, gum, best);
    } else {
        scores_argmax<<<2048, 256, 0, stream>>>(srcE, tgtE, gum, temp, best);
    }
    assemble<<<NB, 1024, 0, stream>>>(src, tgt, best, out);
}

// Round 11
// 205.752 us; speedup vs baseline: 1.1328x; 1.1328x over previous
//
#include <hip/hip_runtime.h>
#include <hip/hip_fp16.h>
#include <math.h>

#define NB 8
#define NC 512
#define NN 2048

typedef __attribute__((ext_vector_type(8))) _Float16 f16x8;
typedef __attribute__((ext_vector_type(4))) float f32x4;

union U8 { uint32_t u[4]; f16x8 v; };

__device__ __forceinline__ unsigned f2mono(float v) {
    unsigned b = __float_as_uint(v);
    return (b & 0x80000000u) ? ~b : (b | 0x80000000u);
}

__device__ __forceinline__ uint32_t packsplit(float a) {
    __half h = __float2half(a);
    float hf = __half2float(h);
    __half lo = __float2half(a - hf);
    return (uint32_t)__half_as_ushort(h) | ((uint32_t)__half_as_ushort(lo) << 16);
}

__device__ __forceinline__ void g2lds16(const void* g, void* l) {
    __builtin_amdgcn_global_load_lds(
        (const __attribute__((address_space(1))) void*)g,
        (__attribute__((address_space(3))) void*)l, 16, 0, 0);
}

// ---------- Kernel P: f32 [b][k][n] -> hi/lo fp16 planes [b][n][k], octet-swizzled ----------
// v2: thread owns 4 consecutive n-rows x 1 octet (8 k) -> float4 reads = 1KB/wave/instr.
// Output bit-identical to v1: P = kt*4 + (o ^ ((n>>1)&3)), hw pairs (2j,2j+1).
extern "C" __global__ __launch_bounds__(256)
void prepack(const float* __restrict__ srcE, const float* __restrict__ tgtE,
             unsigned short* __restrict__ hiA, unsigned short* __restrict__ loA,
             unsigned short* __restrict__ hiB, unsigned short* __restrict__ loB)
{
    const float* in = blockIdx.y ? tgtE : srcE;
    unsigned short* hi = blockIdx.y ? hiB : hiA;
    unsigned short* lo = blockIdx.y ? loB : loA;
    const int t  = blockIdx.x;          // 1024 tiles: 8 b x 16 kt x 8 nt
    const int b  = t >> 7;
    const int kt = (t >> 3) & 15;
    const int nt = t & 7;
    const int k0 = kt * 32, n0 = nt * 256;

    const int tq = threadIdx.x & 63;    // row-quad index (64 quads = 256 rows)
    const int ko = threadIdx.x >> 6;    // octet 0..3 (k = ko*8 .. ko*8+7)
    const int nb = n0 + tq * 4;

    const float* gin = in + (size_t)b * (NC * NN) + (size_t)(k0 + ko * 8) * NN + nb;

    float4 v[8];
#pragma unroll
    for (int j = 0; j < 8; ++j)
        v[j] = *(const float4*)(gin + (size_t)j * NN);   // 64 lanes x 16B = 1KB coalesced

    const float vv[8][4] = {
        {v[0].x, v[0].y, v[0].z, v[0].w}, {v[1].x, v[1].y, v[1].z, v[1].w},
        {v[2].x, v[2].y, v[2].z, v[2].w}, {v[3].x, v[3].y, v[3].z, v[3].w},
        {v[4].x, v[4].y, v[4].z, v[4].w}, {v[5].x, v[5].y, v[5].z, v[5].w},
        {v[6].x, v[6].y, v[6].z, v[6].w}, {v[7].x, v[7].y, v[7].z, v[7].w}};

#pragma unroll
    for (int i = 0; i < 4; ++i) {
        const int n  = nb + i;
        const int s2 = (n >> 1) & 3;
        uint32_t hw[4], lw[4];
#pragma unroll
        for (int jj = 0; jj < 4; ++jj) {
            const float a0 = vv[2 * jj][i], a1 = vv[2 * jj + 1][i];
            const __half h0 = __float2half(a0);
            const __half h1 = __float2half(a1);
            const float d0 = a0 - __half2float(h0);
            const float d1 = a1 - __half2float(h1);
            hw[jj] = (uint32_t)__half_as_ushort(h0) | ((uint32_t)__half_as_ushort(h1) << 16);
            lw[jj] = (uint32_t)__half_as_ushort(__float2half(d0)) |
                     ((uint32_t)__half_as_ushort(__float2half(d1)) << 16);
        }
        const size_t rowbase = ((size_t)b * NN + n) * NC;
        const int P = kt * 4 + (ko ^ s2);
        uint4 qh, ql;
        qh.x = hw[0]; qh.y = hw[1]; qh.z = hw[2]; qh.w = hw[3];
        ql.x = lw[0]; ql.y = lw[1]; ql.z = lw[2]; ql.w = lw[3];
        *(uint4*)(hi + rowbase + (size_t)P * 8) = qh;
        *(uint4*)(lo + rowbase + (size_t)P * 8) = ql;
    }
}

// ---------- Kernel G (R9 verified): 128x128 tile, 4 waves, single 32KB LDS, 16x16x32 MFMA ----------
// planes: 0=A-hi 1=A-lo 2=B-hi 3=B-lo ; [4 plane][128 rows x 32 k] u16 = 32KB -> 3+ blocks/CU
extern "C" __global__ __launch_bounds__(256, 2)
void scores_argmax_sb(const unsigned short* __restrict__ hiA, const unsigned short* __restrict__ loA,
                      const unsigned short* __restrict__ hiB, const unsigned short* __restrict__ loB,
                      const float* __restrict__ gum,
                      unsigned long long* __restrict__ best)
{
    __shared__ unsigned short lds[4][4096];

    const int id = blockIdx.x;
    const int flat = (id & 7) * 256 + (id >> 3);  // XCD swizzle (2048 % 8 == 0, bijective)
    const int mt = flat & 15;
    const int nt = (flat >> 4) & 15;
    const int b  = flat >> 8;
    const int n0 = nt * 128, m0 = mt * 128;

    const int tid = threadIdx.x;
    const int wv = tid >> 6;
    const int l  = tid & 63;
    const int wn = wv >> 1, wm = wv & 1;
    const int row16 = l & 15, h = l >> 4;
    const int s2 = (row16 >> 1) & 3;
    const int fo = (h ^ s2) * 8;      // fragment octet slot (u16 units) — matches prepack swizzle

    // staging: wave wv stages plane wv (verified R5/R9 map)
    const unsigned short* gp;
    int pan;
    if (wv == 0)      { gp = hiA; pan = n0; }
    else if (wv == 1) { gp = loA; pan = n0; }
    else if (wv == 2) { gp = hiB; pan = m0; }
    else              { gp = loB; pan = m0; }
    gp += ((size_t)b * NN + pan) * NC;
    const unsigned short* gl = gp + (size_t)(l >> 2) * NC + (l & 3) * 8;  // + t*32 per K-tile

    f32x4 acc[4][4];
#pragma unroll
    for (int i = 0; i < 4; ++i)
#pragma unroll
        for (int j = 0; j < 4; ++j)
            acc[i][j] = (f32x4){0.f, 0.f, 0.f, 0.f};

#pragma unroll 1
    for (int t = 0; t < 16; ++t) {
        __syncthreads();                    // readers of previous tile done
        {
            const unsigned short* s_ = gl + (size_t)t * 32;
#pragma unroll
            for (int c = 0; c < 8; ++c)
                g2lds16(s_ + (size_t)c * 16 * NC, &lds[wv][c * 512]);
        }
        __syncthreads();                    // compiler drains vmcnt before barrier -> tile ready

        f16x8 bh[4], bl[4];
#pragma unroll
        for (int ms = 0; ms < 4; ++ms) {
            const int r_ = wm * 64 + ms * 16 + row16;
            bh[ms] = *(const f16x8*)&lds[2][r_ * 32 + fo];
            bl[ms] = *(const f16x8*)&lds[3][r_ * 32 + fo];
        }
#pragma unroll
        for (int ns = 0; ns < 4; ++ns) {
            const int r_ = wn * 64 + ns * 16 + row16;
            const f16x8 ah = *(const f16x8*)&lds[0][r_ * 32 + fo];
            const f16x8 al = *(const f16x8*)&lds[1][r_ * 32 + fo];
#pragma unroll
            for (int ms = 0; ms < 4; ++ms) {
                acc[ns][ms] = __builtin_amdgcn_mfma_f32_16x16x32_f16(ah, bh[ms], acc[ns][ms], 0, 0, 0);
                acc[ns][ms] = __builtin_amdgcn_mfma_f32_16x16x32_f16(al, bh[ms], acc[ns][ms], 0, 0, 0);
                acc[ns][ms] = __builtin_amdgcn_mfma_f32_16x16x32_f16(ah, bl[ms], acc[ns][ms], 0, 0, 0);
            }
        }
    }

    // ---- fused gumbel + per-row argmax (fast log; /tau dropped: argmax-invariant, tau>0) ----
    const float SCL = 0.044194173824159216f;  // 1/sqrt(512)
#pragma unroll
    for (int ns = 0; ns < 4; ++ns) {
#pragma unroll
        for (int reg = 0; reg < 4; ++reg) {
            const int n = n0 + wn * 64 + ns * 16 + h * 4 + reg;
            const float* gr = gum + ((size_t)(b * NN + n)) * NN + m0 + wm * 64 + row16;
            unsigned long long bp = 0ULL;
#pragma unroll
            for (int ms = 0; ms < 4; ++ms) {
                float u = gr[ms * 16];
                u = fminf(fmaxf(u, 1e-6f), 1.0f - 1e-6f);
                const float g = -__logf(-__logf(u));
                const float val = fmaf(acc[ns][ms][reg], SCL, g);
                const int m = m0 + wm * 64 + ms * 16 + row16;
                const unsigned long long p =
                    ((unsigned long long)f2mono(val) << 32) | (unsigned)(NN - 1 - m);
                if (p > bp) bp = p;
            }
#pragma unroll
            for (int off = 8; off > 0; off >>= 1) {
                const unsigned long long o = __shfl_xor(bp, off, 16);
                if (o > bp) bp = o;
            }
            if (row16 == 0) atomicMax(&best[(size_t)b * NN + n], bp);
        }
    }
}

// ---------- Fallback (R3 kernel, proven): used only if ws too small ----------
extern "C" __global__ __launch_bounds__(256, 2)
void scores_argmax(const float* __restrict__ srcE,
                   const float* __restrict__ tgtE,
                   const float* __restrict__ gum,
                   const float* __restrict__ temp,
                   unsigned long long* __restrict__ best)
{
    __shared__ uint32_t As[128 * 32];
    __shared__ uint32_t Bs[128 * 32];
    const int id = blockIdx.x;
    const int flat = (id & 7) * 256 + (id >> 3);
    const int mt = flat & 15;
    const int nt = (flat >> 4) & 15;
    const int b  = flat >> 8;
    const int n0 = nt * 128, m0 = mt * 128;

    const int tid = threadIdx.x;
    const int wv = tid >> 6;
    const int l  = tid & 63;
    const int wn = wv >> 1, wm = wv & 1;
    const int row16 = l & 15, h = l >> 4;

    const int snb = 4 * (tid & 31);
    const int skb = tid >> 5;
    const uint32_t sswz = (uint32_t)(tid & 7) << 2;

    const float* Ag = srcE + (size_t)b * NC * NN + n0 + snb;
    const float* Bg = tgtE + (size_t)b * NC * NN + m0 + snb;

    float4 pA[4], pB[4];
#pragma unroll
    for (int r = 0; r < 4; ++r) {
        pA[r] = *(const float4*)(Ag + (size_t)(skb + 8 * r) * NN);
        pB[r] = *(const float4*)(Bg + (size_t)(skb + 8 * r) * NN);
    }

    f32x4 acc[4][4];
#pragma unroll
    for (int i = 0; i < 4; ++i)
#pragma unroll
        for (int j = 0; j < 4; ++j)
            acc[i][j] = (f32x4){0.f, 0.f, 0.f, 0.f};

    for (int k0 = 0; k0 < NC; k0 += 32) {
        __syncthreads();
#pragma unroll
        for (int r = 0; r < 4; ++r) {
            const int k = skb + 8 * r;
            const uint32_t kx = (uint32_t)k ^ sswz;
            uint32_t* ap = &As[snb * 32 + kx];
            uint32_t* bq = &Bs[snb * 32 + kx];
            ap[0]  = packsplit(pA[r].x); ap[32] = packsplit(pA[r].y);
            ap[64] = packsplit(pA[r].z); ap[96] = packsplit(pA[r].w);
            bq[0]  = packsplit(pB[r].x); bq[32] = packsplit(pB[r].y);
            bq[64] = packsplit(pB[r].z); bq[96] = packsplit(pB[r].w);
        }
        if (k0 + 32 < NC) {
#pragma unroll
            for (int r = 0; r < 4; ++r) {
                pA[r] = *(const float4*)(Ag + (size_t)(k0 + 32 + skb + 8 * r) * NN);
                pB[r] = *(const float4*)(Bg + (size_t)(k0 + 32 + skb + 8 * r) * NN);
            }
        }
        __syncthreads();

        U8 bfh[4], bfl[4];
#pragma unroll
        for (int ms = 0; ms < 4; ++ms) {
            const int m_loc = wm * 64 + ms * 16 + row16;
            const uint32_t swz = (uint32_t)((ms * 4 + (row16 >> 2)) & 7) << 2;
            const int base = m_loc * 32;
            const uint4 r0 = *(const uint4*)&Bs[base + (((uint32_t)(h * 8 + 0)) ^ swz)];
            const uint4 r1 = *(const uint4*)&Bs[base + (((uint32_t)(h * 8 + 4)) ^ swz)];
            bfh[ms].u[0] = __builtin_amdgcn_perm(r0.y, r0.x, 0x05040100u);
            bfh[ms].u[1] = __builtin_amdgcn_perm(r0.w, r0.z, 0x05040100u);
            bfh[ms].u[2] = __builtin_amdgcn_perm(r1.y, r1.x, 0x05040100u);
            bfh[ms].u[3] = __builtin_amdgcn_perm(r1.w, r1.z, 0x05040100u);
            bfl[ms].u[0] = __builtin_amdgcn_perm(r0.y, r0.x, 0x07060302u);
            bfl[ms].u[1] = __builtin_amdgcn_perm(r0.w, r0.z, 0x07060302u);
            bfl[ms].u[2] = __builtin_amdgcn_perm(r1.y, r1.x, 0x07060302u);
            bfl[ms].u[3] = __builtin_amdgcn_perm(r1.w, r1.z, 0x07060302u);
        }

#pragma unroll
        for (int ns = 0; ns < 4; ++ns) {
            const int n_loc = wn * 64 + ns * 16 + row16;
            const uint32_t swz = (uint32_t)((ns * 4 + (row16 >> 2)) & 7) << 2;
            const int base = n_loc * 32;
            const uint4 r0 = *(const uint4*)&As[base + (((uint32_t)(h * 8 + 0)) ^ swz)];
            const uint4 r1 = *(const uint4*)&As[base + (((uint32_t)(h * 8 + 4)) ^ swz)];
            U8 ah, al;
            ah.u[0] = __builtin_amdgcn_perm(r0.y, r0.x, 0x05040100u);
            ah.u[1] = __builtin_amdgcn_perm(r0.w, r0.z, 0x05040100u);
            ah.u[2] = __builtin_amdgcn_perm(r1.y, r1.x, 0x05040100u);
            ah.u[3] = __builtin_amdgcn_perm(r1.w, r1.z, 0x05040100u);
            al.u[0] = __builtin_amdgcn_perm(r0.y, r0.x, 0x07060302u);
            al.u[1] = __builtin_amdgcn_perm(r0.w, r0.z, 0x07060302u);
            al.u[2] = __builtin_amdgcn_perm(r1.y, r1.x, 0x07060302u);
            al.u[3] = __builtin_amdgcn_perm(r1.w, r1.z, 0x07060302u);
#pragma unroll
            for (int ms = 0; ms < 4; ++ms) {
                acc[ns][ms] = __builtin_amdgcn_mfma_f32_16x16x32_f16(ah.v, bfh[ms].v, acc[ns][ms], 0, 0, 0);
                acc[ns][ms] = __builtin_amdgcn_mfma_f32_16x16x32_f16(al.v, bfh[ms].v, acc[ns][ms], 0, 0, 0);
                acc[ns][ms] = __builtin_amdgcn_mfma_f32_16x16x32_f16(ah.v, bfl[ms].v, acc[ns][ms], 0, 0, 0);
            }
        }
    }

    const float SCL = 0.044194173824159216f;
    const float tau = temp[b];
#pragma unroll
    for (int ns = 0; ns < 4; ++ns) {
#pragma unroll
        for (int reg = 0; reg < 4; ++reg) {
            const int n = n0 + wn * 64 + ns * 16 + h * 4 + reg;
            const float* gr = gum + ((size_t)(b * NN + n)) * NN + m0 + wm * 64 + row16;
            unsigned long long bp = 0ULL;
#pragma unroll
            for (int ms = 0; ms < 4; ++ms) {
                float u = gr[ms * 16];
                u = fminf(fmaxf(u, 1e-6f), 1.0f - 1e-6f);
                const float g = -logf(-logf(u));
                const float val = (acc[ns][ms][reg] * SCL + g) / tau;
                const int m = m0 + wm * 64 + ms * 16 + row16;
                const unsigned long long p =
                    ((unsigned long long)f2mono(val) << 32) | (unsigned)(NN - 1 - m);
                if (p > bp) bp = p;
            }
#pragma unroll
            for (int off = 8; off > 0; off >>= 1) {
                const unsigned long long o = __shfl_xor(bp, off, 16);
                if (o > bp) bp = o;
            }
            if (row16 == 0) atomicMax(&best[(size_t)b * NN + n], bp);
        }
    }
}

// ---------- Kernel 2: gather + covariance + 3x3 SVD + R,t ----------
__device__ __forceinline__ double det3(const double M[3][3]) {
    return M[0][0] * (M[1][1] * M[2][2] - M[1][2] * M[2][1])
         - M[0][1] * (M[1][0] * M[2][2] - M[1][2] * M[2][0])
         + M[0][2] * (M[1][0] * M[2][1] - M[1][1] * M[2][0]);
}

extern "C" __global__ __launch_bounds__(1024)
void assemble(const float* __restrict__ src, const float* __restrict__ tgt,
              const unsigned long long* __restrict__ best, float* __restrict__ out)
{
    const int b = blockIdx.x;
    const int tid = threadIdx.x;
    float P[9] = {}, Ss[3] = {}, Sc[3] = {};
    for (int n = tid; n < NN; n += 1024) {
        const int m = (NN - 1) - (int)(unsigned)(best[(size_t)b * NN + n] & 0xffffffffu);
        float sv[3], cv[3];
#pragma unroll
        for (int c = 0; c < 3; ++c) {
            sv[c] = src[((size_t)b * 3 + c) * NN + n];
            cv[c] = tgt[((size_t)b * 3 + c) * NN + m];
            Ss[c] += sv[c];
            Sc[c] += cv[c];
        }
#pragma unroll
        for (int c = 0; c < 3; ++c)
#pragma unroll
            for (int d = 0; d < 3; ++d)
                P[c * 3 + d] = fmaf(sv[c], cv[d], P[c * 3 + d]);
    }

    float vals[15];
#pragma unroll
    for (int i = 0; i < 9; ++i) vals[i] = P[i];
#pragma unroll
    for (int i = 0; i < 3; ++i) { vals[9 + i] = Ss[i]; vals[12 + i] = Sc[i]; }

    __shared__ float red[16][15];
    const int lane = tid & 63, wv = tid >> 6;
#pragma unroll
    for (int i = 0; i < 15; ++i) {
        float v = vals[i];
        for (int off = 32; off > 0; off >>= 1) v += __shfl_down(v, off, 64);
        if (lane == 0) red[wv][i] = v;
    }
    __syncthreads();

    if (tid == 0) {
        double tot[15];
        for (int i = 0; i < 15; ++i) {
            double s = 0.0;
            for (int wq = 0; wq < 16; ++wq) s += (double)red[wq][i];
            tot[i] = s;
        }
        double smean[3], cmean[3], H[3][3];
        for (int c = 0; c < 3; ++c) { smean[c] = tot[9 + c] / NN; cmean[c] = tot[12 + c] / NN; }
        for (int c = 0; c < 3; ++c)
            for (int d = 0; d < 3; ++d)
                H[c][d] = tot[c * 3 + d] - tot[9 + c] * tot[12 + d] / NN;

        double W[3][3], V[3][3];
        for (int i = 0; i < 3; ++i)
            for (int j = 0; j < 3; ++j) { W[i][j] = H[i][j]; V[i][j] = (i == j) ? 1.0 : 0.0; }
        for (int sweep = 0; sweep < 60; ++sweep) {
            double offsum = 0.0;
            for (int p = 0; p < 2; ++p)
                for (int q = p + 1; q < 3; ++q) {
                    double al = 0, be = 0, ga = 0;
                    for (int r = 0; r < 3; ++r) {
                        al += W[r][p] * W[r][p];
                        be += W[r][q] * W[r][q];
                        ga += W[r][p] * W[r][q];
                    }
                    offsum += fabs(ga);
                    if (fabs(ga) <= 1e-15 * sqrt(al * be)) continue;
                    double zeta = (be - al) / (2.0 * ga);
                    double t = copysign(1.0, zeta) / (fabs(zeta) + sqrt(1.0 + zeta * zeta));
                    double c = 1.0 / sqrt(1.0 + t * t), s = c * t;
                    for (int r = 0; r < 3; ++r) {
                        double wp = W[r][p], wq = W[r][q];
                        W[r][p] = c * wp - s * wq;
                        W[r][q] = s * wp + c * wq;
                        double vp = V[r][p], vq = V[r][q];
                        V[r][p] = c * vp - s * vq;
                        V[r][q] = s * vp + c * vq;
                    }
                }
            if (offsum < 1e-13) break;
        }
        double S[3];
        for (int i = 0; i < 3; ++i)
            S[i] = sqrt(W[0][i] * W[0][i] + W[1][i] * W[1][i] + W[2][i] * W[2][i]);
        for (int i = 0; i < 2; ++i) {
            int mx = i;
            for (int j = i + 1; j < 3; ++j) if (S[j] > S[mx]) mx = j;
            if (mx != i) {
                double tS = S[i]; S[i] = S[mx]; S[mx] = tS;
                for (int r = 0; r < 3; ++r) {
                    double tw = W[r][i]; W[r][i] = W[r][mx]; W[r][mx] = tw;
                    double tv = V[r][i]; V[r][i] = V[r][mx]; V[r][mx] = tv;
                }
            }
        }
        double U[3][3];
        for (int i = 0; i < 3; ++i) {
            if (S[i] > 1e-12 * S[0] && S[i] > 0.0) {
                for (int r = 0; r < 3; ++r) U[r][i] = W[r][i] / S[i];
            } else {
                double ux = U[1][0] * U[2][1] - U[2][0] * U[1][1];
                double uy = U[2][0] * U[0][1] - U[0][0] * U[2][1];
                double uz = U[0][0] * U[1][1] - U[1][0] * U[0][1];
                double nr = sqrt(ux * ux + uy * uy + uz * uz);
                if (nr < 1e-30) { ux = 1.0; uy = 0.0; uz = 0.0; nr = 1.0; }
                U[0][i] = ux / nr; U[1][i] = uy / nr; U[2][i] = uz / nr;
            }
        }
        double r_[3][3];
        for (int i = 0; i < 3; ++i)
            for (int j = 0; j < 3; ++j)
                r_[i][j] = V[i][0] * U[j][0] + V[i][1] * U[j][1] + V[i][2] * U[j][2];
        double det = det3(r_);
        double R[3][3];
        for (int i = 0; i < 3; ++i)
            for (int j = 0; j < 3; ++j)
                R[i][j] = V[i][0] * U[j][0] + V[i][1] * U[j][1] + det * V[i][2] * U[j][2];
        double t_[3];
        for (int i = 0; i < 3; ++i)
            t_[i] = -(R[i][0] * smean[0] + R[i][1] * smean[1] + R[i][2] * smean[2]) + cmean[i];

        for (int i = 0; i < 3; ++i)
            for (int j = 0; j < 3; ++j)
                out[b * 9 + i * 3 + j] = (float)R[i][j];
        for (int i = 0; i < 3; ++i) out[NB * 9 + b * 3 + i] = (float)t_[i];
    }
}

// ---------- launcher ----------
extern "C" void kernel_launch(void* const* d_in, const int* in_sizes, int n_in,
                              void* d_out, int out_size, void* d_ws, size_t ws_size,
                              hipStream_t stream)
{
    const float* srcE = (const float*)d_in[0];
    const float* tgtE = (const float*)d_in[1];
    const float* src  = (const float*)d_in[2];
    const float* tgt  = (const float*)d_in[3];
    const float* temp = (const float*)d_in[4];
    const float* gum  = (const float*)d_in[5];
    float* out = (float*)d_out;
    unsigned long long* best = (unsigned long long*)d_ws;

    (void)hipMemsetAsync(best, 0, (size_t)NB * NN * sizeof(unsigned long long), stream);

    const size_t PLANE = (size_t)NB * NN * NC;                 // u16 elements per plane
    const size_t NEED  = 131072 + 4 * PLANE * sizeof(unsigned short);  // 128KB + 64MB
    if (ws_size >= NEED) {
        unsigned short* hiA = (unsigned short*)((char*)d_ws + 131072);
        unsigned short* loA = hiA + PLANE;
        unsigned short* hiB = loA + PLANE;
        unsigned short* loB = hiB + PLANE;
        prepack<<<dim3(1024, 2), 256, 0, stream>>>(srcE, tgtE, hiA, loA, hiB, loB);
        scores_argmax_sb<<<2048, 256, 0, stream>>>(hiA, loA, hiB, loB, gum, best);
    } else {
        scores_argmax<<<2048, 256, 0, stream>>>(srcE, tgtE, gum, temp, best);
    }
    assemble<<<NB, 1024, 0, stream>>>(src, tgt, best, out);
}

// Round 12
// 196.637 us; speedup vs baseline: 1.1853x; 1.0463x over previous
//
#include <hip/hip_runtime.h>
#include <hip/hip_fp16.h>
#include <math.h>

#define NB 8
#define NC 512
#define NN 2048

typedef __attribute__((ext_vector_type(8))) _Float16 f16x8;
typedef __attribute__((ext_vector_type(4))) float f32x4;

union U8 { uint32_t u[4]; f16x8 v; };

__device__ __forceinline__ unsigned f2mono(float v) {
    unsigned b = __float_as_uint(v);
    return (b & 0x80000000u) ? ~b : (b | 0x80000000u);
}

__device__ __forceinline__ uint32_t packsplit(float a) {
    __half h = __float2half(a);
    float hf = __half2float(h);
    __half lo = __float2half(a - hf);
    return (uint32_t)__half_as_ushort(h) | ((uint32_t)__half_as_ushort(lo) << 16);
}

__device__ __forceinline__ void g2lds16(const void* g, void* l) {
    __builtin_amdgcn_global_load_lds(
        (const __attribute__((address_space(1))) void*)g,
        (__attribute__((address_space(3))) void*)l, 16, 0, 0);
}

// ---------- Kernel P: f32 [b][k][n] -> hi/lo fp16 planes [b][n][k], octet-swizzled ----------
extern "C" __global__ __launch_bounds__(256)
void prepack(const float* __restrict__ srcE, const float* __restrict__ tgtE,
             unsigned short* __restrict__ hiA, unsigned short* __restrict__ loA,
             unsigned short* __restrict__ hiB, unsigned short* __restrict__ loB)
{
    const float* in = blockIdx.y ? tgtE : srcE;
    unsigned short* hi = blockIdx.y ? hiB : hiA;
    unsigned short* lo = blockIdx.y ? loB : loA;
    const int t  = blockIdx.x;          // 1024 tiles: 8 b x 16 kt x 8 nt
    const int b  = t >> 7;
    const int kt = (t >> 3) & 15;
    const int nt = t & 7;
    const int k0 = kt * 32, n0 = nt * 256;

    const int tq = threadIdx.x & 63;    // row-quad index (64 quads = 256 rows)
    const int ko = threadIdx.x >> 6;    // octet 0..3 (k = ko*8 .. ko*8+7)
    const int nb = n0 + tq * 4;

    const float* gin = in + (size_t)b * (NC * NN) + (size_t)(k0 + ko * 8) * NN + nb;

    float4 v[8];
#pragma unroll
    for (int j = 0; j < 8; ++j)
        v[j] = *(const float4*)(gin + (size_t)j * NN);   // 64 lanes x 16B = 1KB coalesced

    const float vv[8][4] = {
        {v[0].x, v[0].y, v[0].z, v[0].w}, {v[1].x, v[1].y, v[1].z, v[1].w},
        {v[2].x, v[2].y, v[2].z, v[2].w}, {v[3].x, v[3].y, v[3].z, v[3].w},
        {v[4].x, v[4].y, v[4].z, v[4].w}, {v[5].x, v[5].y, v[5].z, v[5].w},
        {v[6].x, v[6].y, v[6].z, v[6].w}, {v[7].x, v[7].y, v[7].z, v[7].w}};

#pragma unroll
    for (int i = 0; i < 4; ++i) {
        const int n  = nb + i;
        const int s2 = (n >> 1) & 3;
        uint32_t hw[4], lw[4];
#pragma unroll
        for (int jj = 0; jj < 4; ++jj) {
            const float a0 = vv[2 * jj][i], a1 = vv[2 * jj + 1][i];
            const __half h0 = __float2half(a0);
            const __half h1 = __float2half(a1);
            const float d0 = a0 - __half2float(h0);
            const float d1 = a1 - __half2float(h1);
            hw[jj] = (uint32_t)__half_as_ushort(h0) | ((uint32_t)__half_as_ushort(h1) << 16);
            lw[jj] = (uint32_t)__half_as_ushort(__float2half(d0)) |
                     ((uint32_t)__half_as_ushort(__float2half(d1)) << 16);
        }
        const size_t rowbase = ((size_t)b * NN + n) * NC;
        const int P = kt * 4 + (ko ^ s2);
        uint4 qh, ql;
        qh.x = hw[0]; qh.y = hw[1]; qh.z = hw[2]; qh.w = hw[3];
        ql.x = lw[0]; ql.y = lw[1]; ql.z = lw[2]; ql.w = lw[3];
        *(uint4*)(hi + rowbase + (size_t)P * 8) = qh;
        *(uint4*)(lo + rowbase + (size_t)P * 8) = ql;
    }
}

// ---------- Kernel G: 256x256 tile, 16 waves (64x64 each), dbuf LDS + counted vmcnt ----------
// planes: 0=A-hi 1=A-lo 2=B-hi 3=B-lo ; LDS [2 buf][4 plane][256 rows x 32 k] u16 = 128KB
// Per-wave code identical to the verified R9 kernel (acc 16xf32x4, same frag maps/swizzle).
extern "C" __global__ __launch_bounds__(1024)
void scores_argmax_256b(const unsigned short* __restrict__ hiA, const unsigned short* __restrict__ loA,
                        const unsigned short* __restrict__ hiB, const unsigned short* __restrict__ loB,
                        const float* __restrict__ gum,
                        unsigned long long* __restrict__ best)
{
    __shared__ unsigned short lds[2][4][8192];

    const int id = blockIdx.x;                  // 512 blocks
    const int flat = (id & 7) * 64 + (id >> 3); // XCD swizzle (512 % 8 == 0, bijective)
    const int b  = flat >> 6;
    const int nt = (flat >> 3) & 7;
    const int mt = flat & 7;
    const int n0 = nt * 256, m0 = mt * 256;

    const int tid = threadIdx.x;
    const int wv = tid >> 6;                    // wave 0..15
    const int l  = tid & 63;
    const int wn = wv >> 2, wm = wv & 3;        // wave tile (wn*64, wm*64) in 256x256
    const int row16 = l & 15, h = l >> 4;
    const int s2 = (row16 >> 1) & 3;
    const int fo = (h ^ s2) * 8;                // fragment octet slot (u16) — prepack swizzle

    // staging: wave wv stages plane (wv>>2), row-quarter (wv&3): 4 g2lds16 per thread
    const int q = wv & 3;
    const unsigned short* gp = (wn == 0) ? hiA : (wn == 1) ? loA : (wn == 2) ? hiB : loB;
    const int pan = (wn < 2) ? n0 : m0;
    const unsigned short* gl = gp + ((size_t)b * NN + pan + q * 64 + (l >> 2)) * NC + (l & 3) * 8;

#define STG(T, BUF) do {                                        \
    const unsigned short* s_ = gl + (size_t)(T) * 32;           \
    unsigned short* d_ = &lds[BUF][wn][q * 2048];               \
    g2lds16(s_,           d_);                                  \
    g2lds16(s_ + 16 * NC, d_ + 512);                            \
    g2lds16(s_ + 32 * NC, d_ + 1024);                           \
    g2lds16(s_ + 48 * NC, d_ + 1536);                           \
} while (0)

    f32x4 acc[4][4];
#pragma unroll
    for (int i = 0; i < 4; ++i)
#pragma unroll
        for (int j = 0; j < 4; ++j)
            acc[i][j] = (f32x4){0.f, 0.f, 0.f, 0.f};

    STG(0, 0);
#pragma unroll 1
    for (int t = 0; t < 16; ++t) {
        if (t < 15) {
            STG(t + 1, (t + 1) & 1);                       // prefetch next tile (other buf)
            asm volatile("s_waitcnt vmcnt(4)" ::: "memory"); // tile t's 4 loads done
        } else {
            asm volatile("s_waitcnt vmcnt(0)" ::: "memory");
        }
        __builtin_amdgcn_sched_barrier(0);
        __builtin_amdgcn_s_barrier();                      // all waves' stage-t complete
        asm volatile("" ::: "memory");

        const unsigned short (*L)[8192] = lds[t & 1];
        f16x8 bh[4], bl[4];
#pragma unroll
        for (int ms = 0; ms < 4; ++ms) {
            const int r_ = wm * 64 + ms * 16 + row16;
            bh[ms] = *(const f16x8*)&L[2][r_ * 32 + fo];
            bl[ms] = *(const f16x8*)&L[3][r_ * 32 + fo];
        }
#pragma unroll
        for (int ns = 0; ns < 4; ++ns) {
            const int r_ = wn * 64 + ns * 16 + row16;
            const f16x8 ah = *(const f16x8*)&L[0][r_ * 32 + fo];
            const f16x8 al = *(const f16x8*)&L[1][r_ * 32 + fo];
#pragma unroll
            for (int ms = 0; ms < 4; ++ms) {
                acc[ns][ms] = __builtin_amdgcn_mfma_f32_16x16x32_f16(ah, bh[ms], acc[ns][ms], 0, 0, 0);
                acc[ns][ms] = __builtin_amdgcn_mfma_f32_16x16x32_f16(al, bh[ms], acc[ns][ms], 0, 0, 0);
                acc[ns][ms] = __builtin_amdgcn_mfma_f32_16x16x32_f16(ah, bl[ms], acc[ns][ms], 0, 0, 0);
            }
        }
        asm volatile("" ::: "memory");
        __builtin_amdgcn_s_barrier();                      // all waves done reading buf t&1
        asm volatile("" ::: "memory");
    }
#undef STG

    // ---- fused gumbel + per-row argmax (fast log; /tau dropped: argmax-invariant, tau>0) ----
    const float SCL = 0.044194173824159216f;  // 1/sqrt(512)
#pragma unroll
    for (int ns = 0; ns < 4; ++ns) {
#pragma unroll
        for (int reg = 0; reg < 4; ++reg) {
            const int n = n0 + wn * 64 + ns * 16 + h * 4 + reg;
            const float* gr = gum + ((size_t)(b * NN + n)) * NN + m0 + wm * 64 + row16;
            unsigned long long bp = 0ULL;
#pragma unroll
            for (int ms = 0; ms < 4; ++ms) {
                float u = gr[ms * 16];
                u = fminf(fmaxf(u, 1e-6f), 1.0f - 1e-6f);
                const float g = -__logf(-__logf(u));
                const float val = fmaf(acc[ns][ms][reg], SCL, g);
                const int m = m0 + wm * 64 + ms * 16 + row16;
                const unsigned long long p =
                    ((unsigned long long)f2mono(val) << 32) | (unsigned)(NN - 1 - m);
                if (p > bp) bp = p;
            }
#pragma unroll
            for (int off = 8; off > 0; off >>= 1) {
                const unsigned long long o = __shfl_xor(bp, off, 16);
                if (o > bp) bp = o;
            }
            if (row16 == 0) atomicMax(&best[(size_t)b * NN + n], bp);
        }
    }
}

// ---------- Fallback (R3 kernel, proven): used only if ws too small ----------
extern "C" __global__ __launch_bounds__(256, 2)
void scores_argmax(const float* __restrict__ srcE,
                   const float* __restrict__ tgtE,
                   const float* __restrict__ gum,
                   const float* __restrict__ temp,
                   unsigned long long* __restrict__ best)
{
    __shared__ uint32_t As[128 * 32];
    __shared__ uint32_t Bs[128 * 32];
    const int id = blockIdx.x;
    const int flat = (id & 7) * 256 + (id >> 3);
    const int mt = flat & 15;
    const int nt = (flat >> 4) & 15;
    const int b  = flat >> 8;
    const int n0 = nt * 128, m0 = mt * 128;

    const int tid = threadIdx.x;
    const int wv = tid >> 6;
    const int l  = tid & 63;
    const int wn = wv >> 1, wm = wv & 1;
    const int row16 = l & 15, h = l >> 4;

    const int snb = 4 * (tid & 31);
    const int skb = tid >> 5;
    const uint32_t sswz = (uint32_t)(tid & 7) << 2;

    const float* Ag = srcE + (size_t)b * NC * NN + n0 + snb;
    const float* Bg = tgtE + (size_t)b * NC * NN + m0 + snb;

    float4 pA[4], pB[4];
#pragma unroll
    for (int r = 0; r < 4; ++r) {
        pA[r] = *(const float4*)(Ag + (size_t)(skb + 8 * r) * NN);
        pB[r] = *(const float4*)(Bg + (size_t)(skb + 8 * r) * NN);
    }

    f32x4 acc[4][4];
#pragma unroll
    for (int i = 0; i < 4; ++i)
#pragma unroll
        for (int j = 0; j < 4; ++j)
            acc[i][j] = (f32x4){0.f, 0.f, 0.f, 0.f};

    for (int k0 = 0; k0 < NC; k0 += 32) {
        __syncthreads();
#pragma unroll
        for (int r = 0; r < 4; ++r) {
            const int k = skb + 8 * r;
            const uint32_t kx = (uint32_t)k ^ sswz;
            uint32_t* ap = &As[snb * 32 + kx];
            uint32_t* bq = &Bs[snb * 32 + kx];
            ap[0]  = packsplit(pA[r].x); ap[32] = packsplit(pA[r].y);
            ap[64] = packsplit(pA[r].z); ap[96] = packsplit(pA[r].w);
            bq[0]  = packsplit(pB[r].x); bq[32] = packsplit(pB[r].y);
            bq[64] = packsplit(pB[r].z); bq[96] = packsplit(pB[r].w);
        }
        if (k0 + 32 < NC) {
#pragma unroll
            for (int r = 0; r < 4; ++r) {
                pA[r] = *(const float4*)(Ag + (size_t)(k0 + 32 + skb + 8 * r) * NN);
                pB[r] = *(const float4*)(Bg + (size_t)(k0 + 32 + skb + 8 * r) * NN);
            }
        }
        __syncthreads();

        U8 bfh[4], bfl[4];
#pragma unroll
        for (int ms = 0; ms < 4; ++ms) {
            const int m_loc = wm * 64 + ms * 16 + row16;
            const uint32_t swz = (uint32_t)((ms * 4 + (row16 >> 2)) & 7) << 2;
            const int base = m_loc * 32;
            const uint4 r0 = *(const uint4*)&Bs[base + (((uint32_t)(h * 8 + 0)) ^ swz)];
            const uint4 r1 = *(const uint4*)&Bs[base + (((uint32_t)(h * 8 + 4)) ^ swz)];
            bfh[ms].u[0] = __builtin_amdgcn_perm(r0.y, r0.x, 0x05040100u);
            bfh[ms].u[1] = __builtin_amdgcn_perm(r0.w, r0.z, 0x05040100u);
            bfh[ms].u[2] = __builtin_amdgcn_perm(r1.y, r1.x, 0x05040100u);
            bfh[ms].u[3] = __builtin_amdgcn_perm(r1.w, r1.z, 0x05040100u);
            bfl[ms].u[0] = __builtin_amdgcn_perm(r0.y, r0.x, 0x07060302u);
            bfl[ms].u[1] = __builtin_amdgcn_perm(r0.w, r0.z, 0x07060302u);
            bfl[ms].u[2] = __builtin_amdgcn_perm(r1.y, r1.x, 0x07060302u);
            bfl[ms].u[3] = __builtin_amdgcn_perm(r1.w, r1.z, 0x07060302u);
        }

#pragma unroll
        for (int ns = 0; ns < 4; ++ns) {
            const int n_loc = wn * 64 + ns * 16 + row16;
            const uint32_t swz = (uint32_t)((ns * 4 + (row16 >> 2)) & 7) << 2;
            const int base = n_loc * 32;
            const uint4 r0 = *(const uint4*)&As[base + (((uint32_t)(h * 8 + 0)) ^ swz)];
            const uint4 r1 = *(const uint4*)&As[base + (((uint32_t)(h * 8 + 4)) ^ swz)];
            U8 ah, al;
            ah.u[0] = __builtin_amdgcn_perm(r0.y, r0.x, 0x05040100u);
            ah.u[1] = __builtin_amdgcn_perm(r0.w, r0.z, 0x05040100u);
            ah.u[2] = __builtin_amdgcn_perm(r1.y, r1.x, 0x05040100u);
            ah.u[3] = __builtin_amdgcn_perm(r1.w, r1.z, 0x05040100u);
            al.u[0] = __builtin_amdgcn_perm(r0.y, r0.x, 0x07060302u);
            al.u[1] = __builtin_amdgcn_perm(r0.w, r0.z, 0x07060302u);
            al.u[2] = __builtin_amdgcn_perm(r1.y, r1.x, 0x07060302u);
            al.u[3] = __builtin_amdgcn_perm(r1.w, r1.z, 0x07060302u);
#pragma unroll
            for (int ms = 0; ms < 4; ++ms) {
                acc[ns][ms] = __builtin_amdgcn_mfma_f32_16x16x32_f16(ah.v, bfh[ms].v, acc[ns][ms], 0, 0, 0);
                acc[ns][ms] = __builtin_amdgcn_mfma_f32_16x16x32_f16(al.v, bfh[ms].v, acc[ns][ms], 0, 0, 0);
                acc[ns][ms] = __builtin_amdgcn_mfma_f32_16x16x32_f16(ah.v, bfl[ms].v, acc[ns][ms], 0, 0, 0);
            }
        }
    }

    const float SCL = 0.044194173824159216f;
    const float tau = temp[b];
#pragma unroll
    for (int ns = 0; ns < 4; ++ns) {
#pragma unroll
        for (int reg = 0; reg < 4; ++reg) {
            const int n = n0 + wn * 64 + ns * 16 + h * 4 + reg;
            const float* gr = gum + ((size_t)(b * NN + n)) * NN + m0 + wm * 64 + row16;
            unsigned long long bp = 0ULL;
#pragma unroll
            for (int ms = 0; ms < 4; ++ms) {
                float u = gr[ms * 16];
                u = fminf(fmaxf(u, 1e-6f), 1.0f - 1e-6f);
                const float g = -logf(-logf(u));
                const float val = (acc[ns][ms][reg] * SCL + g) / tau;
                const int m = m0 + wm * 64 + ms * 16 + row16;
                const unsigned long long p =
                    ((unsigned long long)f2mono(val) << 32) | (unsigned)(NN - 1 - m);
                if (p > bp) bp = p;
            }
#pragma unroll
            for (int off = 8; off > 0; off >>= 1) {
                const unsigned long long o = __shfl_xor(bp, off, 16);
                if (o > bp) bp = o;
            }
            if (row16 == 0) atomicMax(&best[(size_t)b * NN + n], bp);
        }
    }
}

// ---------- Kernel 2: gather + covariance + 3x3 SVD + R,t ----------
__device__ __forceinline__ double det3(const double M[3][3]) {
    return M[0][0] * (M[1][1] * M[2][2] - M[1][2] * M[2][1])
         - M[0][1] * (M[1][0] * M[2][2] - M[1][2] * M[2][0])
         + M[0][2] * (M[1][0] * M[2][1] - M[1][1] * M[2][0]);
}

extern "C" __global__ __launch_bounds__(1024)
void assemble(const float* __restrict__ src, const float* __restrict__ tgt,
              const unsigned long long* __restrict__ best, float* __restrict__ out)
{
    const int b = blockIdx.x;
    const int tid = threadIdx.x;
    float P[9] = {}, Ss[3] = {}, Sc[3] = {};
    for (int n = tid; n < NN; n += 1024) {
        const int m = (NN - 1) - (int)(unsigned)(best[(size_t)b * NN + n] & 0xffffffffu);
        float sv[3], cv[3];
#pragma unroll
        for (int c = 0; c < 3; ++c) {
            sv[c] = src[((size_t)b * 3 + c) * NN + n];
            cv[c] = tgt[((size_t)b * 3 + c) * NN + m];
            Ss[c] += sv[c];
            Sc[c] += cv[c];
        }
#pragma unroll
        for (int c = 0; c < 3; ++c)
#pragma unroll
            for (int d = 0; d < 3; ++d)
                P[c * 3 + d] = fmaf(sv[c], cv[d], P[c * 3 + d]);
    }

    float vals[15];
#pragma unroll
    for (int i = 0; i < 9; ++i) vals[i] = P[i];
#pragma unroll
    for (int i = 0; i < 3; ++i) { vals[9 + i] = Ss[i]; vals[12 + i] = Sc[i]; }

    __shared__ float red[16][15];
    const int lane = tid & 63, wv = tid >> 6;
#pragma unroll
    for (int i = 0; i < 15; ++i) {
        float v = vals[i];
        for (int off = 32; off > 0; off >>= 1) v += __shfl_down(v, off, 64);
        if (lane == 0) red[wv][i] = v;
    }
    __syncthreads();

    if (tid == 0) {
        double tot[15];
        for (int i = 0; i < 15; ++i) {
            double s = 0.0;
            for (int wq = 0; wq < 16; ++wq) s += (double)red[wq][i];
            tot[i] = s;
        }
        double smean[3], cmean[3], H[3][3];
        for (int c = 0; c < 3; ++c) { smean[c] = tot[9 + c] / NN; cmean[c] = tot[12 + c] / NN; }
        for (int c = 0; c < 3; ++c)
            for (int d = 0; d < 3; ++d)
                H[c][d] = tot[c * 3 + d] - tot[9 + c] * tot[12 + d] / NN;

        double W[3][3], V[3][3];
        for (int i = 0; i < 3; ++i)
            for (int j = 0; j < 3; ++j) { W[i][j] = H[i][j]; V[i][j] = (i == j) ? 1.0 : 0.0; }
        for (int sweep = 0; sweep < 60; ++sweep) {
            double offsum = 0.0;
            for (int p = 0; p < 2; ++p)
                for (int q = p + 1; q < 3; ++q) {
                    double al = 0, be = 0, ga = 0;
                    for (int r = 0; r < 3; ++r) {
                        al += W[r][p] * W[r][p];
                        be += W[r][q] * W[r][q];
                        ga += W[r][p] * W[r][q];
                    }
                    offsum += fabs(ga);
                    if (fabs(ga) <= 1e-15 * sqrt(al * be)) continue;
                    double zeta = (be - al) / (2.0 * ga);
                    double t = copysign(1.0, zeta) / (fabs(zeta) + sqrt(1.0 + zeta * zeta));
                    double c = 1.0 / sqrt(1.0 + t * t), s = c * t;
                    for (int r = 0; r < 3; ++r) {
                        double wp = W[r][p], wq = W[r][q];
                        W[r][p] = c * wp - s * wq;
                        W[r][q] = s * wp + c * wq;
                        double vp = V[r][p], vq = V[r][q];
                        V[r][p] = c * vp - s * vq;
                        V[r][q] = s * vp + c * vq;
                    }
                }
            if (offsum < 1e-13) break;
        }
        double S[3];
        for (int i = 0; i < 3; ++i)
            S[i] = sqrt(W[0][i] * W[0][i] + W[1][i] * W[1][i] + W[2][i] * W[2][i]);
        for (int i = 0; i < 2; ++i) {
            int mx = i;
            for (int j = i + 1; j < 3; ++j) if (S[j] > S[mx]) mx = j;
            if (mx != i) {
                double tS = S[i]; S[i] = S[mx]; S[mx] = tS;
                for (int r = 0; r < 3; ++r) {
                    double tw = W[r][i]; W[r][i] = W[r][mx]; W[r][mx] = tw;
                    double tv = V[r][i]; V[r][i] = V[r][mx]; V[r][mx] = tv;
                }
            }
        }
        double U[3][3];
        for (int i = 0; i < 3; ++i) {
            if (S[i] > 1e-12 * S[0] && S[i] > 0.0) {
                for (int r = 0; r < 3; ++r) U[r][i] = W[r][i] / S[i];
            } else {
                double ux = U[1][0] * U[2][1] - U[2][0] * U[1][1];
                double uy = U[2][0] * U[0][1] - U[0][0] * U[2][1];
                double uz = U[0][0] * U[1][1] - U[1][0] * U[0][1];
                double nr = sqrt(ux * ux + uy * uy + uz * uz);
                if (nr < 1e-30) { ux = 1.0; uy = 0.0; uz = 0.0; nr = 1.0; }
                U[0][i] = ux / nr; U[1][i] = uy / nr; U[2][i] = uz / nr;
            }
        }
        double r_[3][3];
        for (int i = 0; i < 3; ++i)
            for (int j = 0; j < 3; ++j)
                r_[i][j] = V[i][0] * U[j][0] + V[i][1] * U[j][1] + V[i][2] * U[j][2];
        double det = det3(r_);
        double R[3][3];
        for (int i = 0; i < 3; ++i)
            for (int j = 0; j < 3; ++j)
                R[i][j] = V[i][0] * U[j][0] + V[i][1] * U[j][1] + det * V[i][2] * U[j][2];
        double t_[3];
        for (int i = 0; i < 3; ++i)
            t_[i] = -(R[i][0] * smean[0] + R[i][1] * smean[1] + R[i][2] * smean[2]) + cmean[i];

        for (int i = 0; i < 3; ++i)
            for (int j = 0; j < 3; ++j)
                out[b * 9 + i * 3 + j] = (float)R[i][j];
        for (int i = 0; i < 3; ++i) out[NB * 9 + b * 3 + i] = (float)t_[i];
    }
}

// ---------- launcher ----------
extern "C" void kernel_launch(void* const* d_in, const int* in_sizes, int n_in,
                              void* d_out, int out_size, void* d_ws, size_t ws_size,
                              hipStream_t stream)
{
    const float* srcE = (const float*)d_in[0];
    const float* tgtE = (const float*)d_in[1];
    const float* src  = (const float*)d_in[2];
    const float* tgt  = (const float*)d_in[3];
    const float* temp = (const float*)d_in[4];
    const float* gum  = (const float*)d_in[5];
    float* out = (float*)d_out;
    unsigned long long* best = (unsigned long long*)d_ws;

    (void)hipMemsetAsync(best, 0, (size_t)NB * NN * sizeof(unsigned long long), stream);

    const size_t PLANE = (size_t)NB * NN * NC;                 // u16 elements per plane
    const size_t NEED  = 131072 + 4 * PLANE * sizeof(unsigned short);  // 128KB + 64MB
    if (ws_size >= NEED) {
        unsigned short* hiA = (unsigned short*)((char*)d_ws + 131072);
        unsigned short* loA = hiA + PLANE;
        unsigned short* hiB = loA + PLANE;
        unsigned short* loB = hiB + PLANE;
        prepack<<<dim3(1024, 2), 256, 0, stream>>>(srcE, tgtE, hiA, loA, hiB, loB);
        scores_argmax_256b<<<512, 1024, 0, stream>>>(hiA, loA, hiB, loB, gum, best);
    } else {
        scores_argmax<<<2048, 256, 0, stream>>>(srcE, tgtE, gum, temp, best);
    }
    assemble<<<NB, 1024, 0, stream>>>(src, tgt, best, out);
}

// Round 13
// 184.715 us; speedup vs baseline: 1.2618x; 1.0645x over previous
//
#include <hip/hip_runtime.h>
#include <hip/hip_fp16.h>
#include <math.h>

#define NB 8
#define NC 512
#define NN 2048

typedef __attribute__((ext_vector_type(8))) _Float16 f16x8;
typedef __attribute__((ext_vector_type(4))) float f32x4;

union U8 { uint32_t u[4]; f16x8 v; };

__device__ __forceinline__ unsigned f2mono(float v) {
    unsigned b = __float_as_uint(v);
    return (b & 0x80000000u) ? ~b : (b | 0x80000000u);
}

__device__ __forceinline__ uint32_t packsplit(float a) {
    __half h = __float2half(a);
    float hf = __half2float(h);
    __half lo = __float2half(a - hf);
    return (uint32_t)__half_as_ushort(h) | ((uint32_t)__half_as_ushort(lo) << 16);
}

__device__ __forceinline__ void g2lds16(const void* g, void* l) {
    __builtin_amdgcn_global_load_lds(
        (const __attribute__((address_space(1))) void*)g,
        (__attribute__((address_space(3))) void*)l, 16, 0, 0);
}

// ---------- Kernel P v3: f32 [b][k][n] -> hi/lo fp16 planes, K-TILE-MAJOR [b][kt][n][32] ----------
// Row (b,kt,n) occupies a contiguous 64B line at ((b*16+kt)*NN + n)*32 u16; octet o stored at
// slot o ^ ((n>>1)&3) within the line (same within-row swizzle as before -> LDS contents identical).
// Each thread produces the FULL 64B hi-line + 64B lo-line of one row -> block writes one
// contiguous 16KB span per plane (fully coalesced; no cross-wave line assembly).
extern "C" __global__ __launch_bounds__(256)
void prepack(const float* __restrict__ srcE, const float* __restrict__ tgtE,
             unsigned short* __restrict__ hiA, unsigned short* __restrict__ loA,
             unsigned short* __restrict__ hiB, unsigned short* __restrict__ loB)
{
    const float* in = blockIdx.y ? tgtE : srcE;
    unsigned short* hi = blockIdx.y ? hiB : hiA;
    unsigned short* lo = blockIdx.y ? loB : loA;
    const int t  = blockIdx.x;          // 1024 tiles: 8 b x 16 kt x 8 nt
    const int b  = t >> 7;
    const int kt = (t >> 3) & 15;
    const int nt = t & 7;
    const int k0 = kt * 32, n0 = nt * 256;

    const int n_l = threadIdx.x;        // thread owns one n-row of the 32-k slab
    const int n   = n0 + n_l;
    const int s2  = (n >> 1) & 3;
    const float* gin = in + (size_t)b * (NC * NN) + (size_t)k0 * NN + n;

    float v[32];
#pragma unroll
    for (int k = 0; k < 32; ++k) v[k] = gin[(size_t)k * NN];   // coalesced across threads

    uint32_t hw[16], lw[16];
#pragma unroll
    for (int j = 0; j < 16; ++j) {
        __half h0 = __float2half(v[2*j]);
        __half h1 = __float2half(v[2*j+1]);
        float  d0 = v[2*j]   - __half2float(h0);
        float  d1 = v[2*j+1] - __half2float(h1);
        hw[j] = (uint32_t)__half_as_ushort(h0) | ((uint32_t)__half_as_ushort(h1) << 16);
        lw[j] = (uint32_t)__half_as_ushort(__float2half(d0)) |
                ((uint32_t)__half_as_ushort(__float2half(d1)) << 16);
    }
    const size_t rowbase = ((size_t)(b * 16 + kt) * NN + n) * 32;   // k-tile-major
#pragma unroll
    for (int o = 0; o < 4; ++o) {
        const int P = o ^ s2;           // octet slot within the 64B line
        uint4 qh, ql;
        qh.x = hw[4*o+0]; qh.y = hw[4*o+1]; qh.z = hw[4*o+2]; qh.w = hw[4*o+3];
        ql.x = lw[4*o+0]; ql.y = lw[4*o+1]; ql.z = lw[4*o+2]; ql.w = lw[4*o+3];
        *(uint4*)(hi + rowbase + (size_t)P * 8) = qh;
        *(uint4*)(lo + rowbase + (size_t)P * 8) = ql;
    }
}

// ---------- Kernel G: 256x256 tile, 16 waves (64x64 each), dbuf LDS + counted vmcnt ----------
// planes: 0=A-hi 1=A-lo 2=B-hi 3=B-lo ; LDS [2 buf][4 plane][256 rows x 32 k] u16 = 128KB
// Per-wave code identical to the verified R9/R12 kernel; staging addresses updated for
// k-tile-major plane layout (tile t's data is one contiguous 128KB region per plane-panel).
extern "C" __global__ __launch_bounds__(1024)
void scores_argmax_256b(const unsigned short* __restrict__ hiA, const unsigned short* __restrict__ loA,
                        const unsigned short* __restrict__ hiB, const unsigned short* __restrict__ loB,
                        const float* __restrict__ gum,
                        unsigned long long* __restrict__ best)
{
    __shared__ unsigned short lds[2][4][8192];

    const int id = blockIdx.x;                  // 512 blocks
    const int flat = (id & 7) * 64 + (id >> 3); // XCD swizzle (512 % 8 == 0, bijective)
    const int b  = flat >> 6;
    const int nt = (flat >> 3) & 7;
    const int mt = flat & 7;
    const int n0 = nt * 256, m0 = mt * 256;

    const int tid = threadIdx.x;
    const int wv = tid >> 6;                    // wave 0..15
    const int l  = tid & 63;
    const int wn = wv >> 2, wm = wv & 3;        // wave tile (wn*64, wm*64) in 256x256
    const int row16 = l & 15, h = l >> 4;
    const int s2 = (row16 >> 1) & 3;
    const int fo = (h ^ s2) * 8;                // fragment octet slot (u16) — prepack swizzle

    // staging: wave wv stages plane (wv>>2), row-quarter (wv&3): 4 g2lds16 per thread
    const int q = wv & 3;
    const unsigned short* gp = (wn == 0) ? hiA : (wn == 1) ? loA : (wn == 2) ? hiB : loB;
    const int pan = (wn < 2) ? n0 : m0;
    // k-tile-major: row (b, t, n) at ((b*16+t)*NN + n)*32
    const unsigned short* gl0 = gp + ((size_t)(b * 16) * NN + pan + q * 64 + (l >> 2)) * 32 + (l & 3) * 8;

#define STG(T, BUF) do {                                        \
    const unsigned short* s_ = gl0 + (size_t)(T) * (NN * 32);   \
    unsigned short* d_ = &lds[BUF][wn][q * 2048];               \
    g2lds16(s_,            d_);                                 \
    g2lds16(s_ + 16 * 32,  d_ + 512);                           \
    g2lds16(s_ + 32 * 32,  d_ + 1024);                          \
    g2lds16(s_ + 48 * 32,  d_ + 1536);                          \
} while (0)

    f32x4 acc[4][4];
#pragma unroll
    for (int i = 0; i < 4; ++i)
#pragma unroll
        for (int j = 0; j < 4; ++j)
            acc[i][j] = (f32x4){0.f, 0.f, 0.f, 0.f};

    STG(0, 0);
#pragma unroll 1
    for (int t = 0; t < 16; ++t) {
        if (t < 15) {
            STG(t + 1, (t + 1) & 1);                       // prefetch next tile (other buf)
            asm volatile("s_waitcnt vmcnt(4)" ::: "memory"); // tile t's 4 loads done
        } else {
            asm volatile("s_waitcnt vmcnt(0)" ::: "memory");
        }
        __builtin_amdgcn_sched_barrier(0);
        __builtin_amdgcn_s_barrier();                      // all waves' stage-t complete
        asm volatile("" ::: "memory");

        const unsigned short (*L)[8192] = lds[t & 1];
        f16x8 bh[4], bl[4];
#pragma unroll
        for (int ms = 0; ms < 4; ++ms) {
            const int r_ = wm * 64 + ms * 16 + row16;
            bh[ms] = *(const f16x8*)&L[2][r_ * 32 + fo];
            bl[ms] = *(const f16x8*)&L[3][r_ * 32 + fo];
        }
#pragma unroll
        for (int ns = 0; ns < 4; ++ns) {
            const int r_ = wn * 64 + ns * 16 + row16;
            const f16x8 ah = *(const f16x8*)&L[0][r_ * 32 + fo];
            const f16x8 al = *(const f16x8*)&L[1][r_ * 32 + fo];
#pragma unroll
            for (int ms = 0; ms < 4; ++ms) {
                acc[ns][ms] = __builtin_amdgcn_mfma_f32_16x16x32_f16(ah, bh[ms], acc[ns][ms], 0, 0, 0);
                acc[ns][ms] = __builtin_amdgcn_mfma_f32_16x16x32_f16(al, bh[ms], acc[ns][ms], 0, 0, 0);
                acc[ns][ms] = __builtin_amdgcn_mfma_f32_16x16x32_f16(ah, bl[ms], acc[ns][ms], 0, 0, 0);
            }
        }
        asm volatile("" ::: "memory");
        __builtin_amdgcn_s_barrier();                      // all waves done reading buf t&1
        asm volatile("" ::: "memory");
    }
#undef STG

    // ---- fused gumbel + per-row argmax (fast log; /tau dropped: argmax-invariant, tau>0) ----
    const float SCL = 0.044194173824159216f;  // 1/sqrt(512)
#pragma unroll
    for (int ns = 0; ns < 4; ++ns) {
#pragma unroll
        for (int reg = 0; reg < 4; ++reg) {
            const int n = n0 + wn * 64 + ns * 16 + h * 4 + reg;
            const float* gr = gum + ((size_t)(b * NN + n)) * NN + m0 + wm * 64 + row16;
            unsigned long long bp = 0ULL;
#pragma unroll
            for (int ms = 0; ms < 4; ++ms) {
                float u = gr[ms * 16];
                u = fminf(fmaxf(u, 1e-6f), 1.0f - 1e-6f);
                const float g = -__logf(-__logf(u));
                const float val = fmaf(acc[ns][ms][reg], SCL, g);
                const int m = m0 + wm * 64 + ms * 16 + row16;
                const unsigned long long p =
                    ((unsigned long long)f2mono(val) << 32) | (unsigned)(NN - 1 - m);
                if (p > bp) bp = p;
            }
#pragma unroll
            for (int off = 8; off > 0; off >>= 1) {
                const unsigned long long o = __shfl_xor(bp, off, 16);
                if (o > bp) bp = o;
            }
            if (row16 == 0) atomicMax(&best[(size_t)b * NN + n], bp);
        }
    }
}

// ---------- Fallback (R3 kernel, proven): used only if ws too small ----------
extern "C" __global__ __launch_bounds__(256, 2)
void scores_argmax(const float* __restrict__ srcE,
                   const float* __restrict__ tgtE,
                   const float* __restrict__ gum,
                   const float* __restrict__ temp,
                   unsigned long long* __restrict__ best)
{
    __shared__ uint32_t As[128 * 32];
    __shared__ uint32_t Bs[128 * 32];
    const int id = blockIdx.x;
    const int flat = (id & 7) * 256 + (id >> 3);
    const int mt = flat & 15;
    const int nt = (flat >> 4) & 15;
    const int b  = flat >> 8;
    const int n0 = nt * 128, m0 = mt * 128;

    const int tid = threadIdx.x;
    const int wv = tid >> 6;
    const int l  = tid & 63;
    const int wn = wv >> 1, wm = wv & 1;
    const int row16 = l & 15, h = l >> 4;

    const int snb = 4 * (tid & 31);
    const int skb = tid >> 5;
    const uint32_t sswz = (uint32_t)(tid & 7) << 2;

    const float* Ag = srcE + (size_t)b * NC * NN + n0 + snb;
    const float* Bg = tgtE + (size_t)b * NC * NN + m0 + snb;

    float4 pA[4], pB[4];
#pragma unroll
    for (int r = 0; r < 4; ++r) {
        pA[r] = *(const float4*)(Ag + (size_t)(skb + 8 * r) * NN);
        pB[r] = *(const float4*)(Bg + (size_t)(skb + 8 * r) * NN);
    }

    f32x4 acc[4][4];
#pragma unroll
    for (int i = 0; i < 4; ++i)
#pragma unroll
        for (int j = 0; j < 4; ++j)
            acc[i][j] = (f32x4){0.f, 0.f, 0.f, 0.f};

    for (int k0 = 0; k0 < NC; k0 += 32) {
        __syncthreads();
#pragma unroll
        for (int r = 0; r < 4; ++r) {
            const int k = skb + 8 * r;
            const uint32_t kx = (uint32_t)k ^ sswz;
            uint32_t* ap = &As[snb * 32 + kx];
            uint32_t* bq = &Bs[snb * 32 + kx];
            ap[0]  = packsplit(pA[r].x); ap[32] = packsplit(pA[r].y);
            ap[64] = packsplit(pA[r].z); ap[96] = packsplit(pA[r].w);
            bq[0]  = packsplit(pB[r].x); bq[32] = packsplit(pB[r].y);
            bq[64] = packsplit(pB[r].z); bq[96] = packsplit(pB[r].w);
        }
        if (k0 + 32 < NC) {
#pragma unroll
            for (int r = 0; r < 4; ++r) {
                pA[r] = *(const float4*)(Ag + (size_t)(k0 + 32 + skb + 8 * r) * NN);
                pB[r] = *(const float4*)(Bg + (size_t)(k0 + 32 + skb + 8 * r) * NN);
            }
        }
        __syncthreads();

        U8 bfh[4], bfl[4];
#pragma unroll
        for (int ms = 0; ms < 4; ++ms) {
            const int m_loc = wm * 64 + ms * 16 + row16;
            const uint32_t swz = (uint32_t)((ms * 4 + (row16 >> 2)) & 7) << 2;
            const int base = m_loc * 32;
            const uint4 r0 = *(const uint4*)&Bs[base + (((uint32_t)(h * 8 + 0)) ^ swz)];
            const uint4 r1 = *(const uint4*)&Bs[base + (((uint32_t)(h * 8 + 4)) ^ swz)];
            bfh[ms].u[0] = __builtin_amdgcn_perm(r0.y, r0.x, 0x05040100u);
            bfh[ms].u[1] = __builtin_amdgcn_perm(r0.w, r0.z, 0x05040100u);
            bfh[ms].u[2] = __builtin_amdgcn_perm(r1.y, r1.x, 0x05040100u);
            bfh[ms].u[3] = __builtin_amdgcn_perm(r1.w, r1.z, 0x05040100u);
            bfl[ms].u[0] = __builtin_amdgcn_perm(r0.y, r0.x, 0x07060302u);
            bfl[ms].u[1] = __builtin_amdgcn_perm(r0.w, r0.z, 0x07060302u);
            bfl[ms].u[2] = __builtin_amdgcn_perm(r1.y, r1.x, 0x07060302u);
            bfl[ms].u[3] = __builtin_amdgcn_perm(r1.w, r1.z, 0x07060302u);
        }

#pragma unroll
        for (int ns = 0; ns < 4; ++ns) {
            const int n_loc = wn * 64 + ns * 16 + row16;
            const uint32_t swz = (uint32_t)((ns * 4 + (row16 >> 2)) & 7) << 2;
            const int base = n_loc * 32;
            const uint4 r0 = *(const uint4*)&As[base + (((uint32_t)(h * 8 + 0)) ^ swz)];
            const uint4 r1 = *(const uint4*)&As[base + (((uint32_t)(h * 8 + 4)) ^ swz)];
            U8 ah, al;
            ah.u[0] = __builtin_amdgcn_perm(r0.y, r0.x, 0x05040100u);
            ah.u[1] = __builtin_amdgcn_perm(r0.w, r0.z, 0x05040100u);
            ah.u[2] = __builtin_amdgcn_perm(r1.y, r1.x, 0x05040100u);
            ah.u[3] = __builtin_amdgcn_perm(r1.w, r1.z, 0x05040100u);
            al.u[0] = __builtin_amdgcn_perm(r0.y, r0.x, 0x07060302u);
            al.u[1] = __builtin_amdgcn_perm(r0.w, r0.z, 0x07060302u);
            al.u[2] = __builtin_amdgcn_perm(r1.y, r1.x, 0x07060302u);
            al.u[3] = __builtin_amdgcn_perm(r1.w, r1.z, 0x07060302u);
#pragma unroll
            for (int ms = 0; ms < 4; ++ms) {
                acc[ns][ms] = __builtin_amdgcn_mfma_f32_16x16x32_f16(ah.v, bfh[ms].v, acc[ns][ms], 0, 0, 0);
                acc[ns][ms] = __builtin_amdgcn_mfma_f32_16x16x32_f16(al.v, bfh[ms].v, acc[ns][ms], 0, 0, 0);
                acc[ns][ms] = __builtin_amdgcn_mfma_f32_16x16x32_f16(ah.v, bfl[ms].v, acc[ns][ms], 0, 0, 0);
            }
        }
    }

    const float SCL = 0.044194173824159216f;
    const float tau = temp[b];
#pragma unroll
    for (int ns = 0; ns < 4; ++ns) {
#pragma unroll
        for (int reg = 0; reg < 4; ++reg) {
            const int n = n0 + wn * 64 + ns * 16 + h * 4 + reg;
            const float* gr = gum + ((size_t)(b * NN + n)) * NN + m0 + wm * 64 + row16;
            unsigned long long bp = 0ULL;
#pragma unroll
            for (int ms = 0; ms < 4; ++ms) {
                float u = gr[ms * 16];
                u = fminf(fmaxf(u, 1e-6f), 1.0f - 1e-6f);
                const float g = -logf(-logf(u));
                const float val = (acc[ns][ms][reg] * SCL + g) / tau;
                const int m = m0 + wm * 64 + ms * 16 + row16;
                const unsigned long long p =
                    ((unsigned long long)f2mono(val) << 32) | (unsigned)(NN - 1 - m);
                if (p > bp) bp = p;
            }
#pragma unroll
            for (int off = 8; off > 0; off >>= 1) {
                const unsigned long long o = __shfl_xor(bp, off, 16);
                if (o > bp) bp = o;
            }
            if (row16 == 0) atomicMax(&best[(size_t)b * NN + n], bp);
        }
    }
}

// ---------- Kernel 2: gather + covariance + 3x3 SVD + R,t ----------
__device__ __forceinline__ double det3(const double M[3][3]) {
    return M[0][0] * (M[1][1] * M[2][2] - M[1][2] * M[2][1])
         - M[0][1] * (M[1][0] * M[2][2] - M[1][2] * M[2][0])
         + M[0][2] * (M[1][0] * M[2][1] - M[1][1] * M[2][0]);
}

extern "C" __global__ __launch_bounds__(1024)
void assemble(const float* __restrict__ src, const float* __restrict__ tgt,
              const unsigned long long* __restrict__ best, float* __restrict__ out)
{
    const int b = blockIdx.x;
    const int tid = threadIdx.x;
    float P[9] = {}, Ss[3] = {}, Sc[3] = {};
    for (int n = tid; n < NN; n += 1024) {
        const int m = (NN - 1) - (int)(unsigned)(best[(size_t)b * NN + n] & 0xffffffffu);
        float sv[3], cv[3];
#pragma unroll
        for (int c = 0; c < 3; ++c) {
            sv[c] = src[((size_t)b * 3 + c) * NN + n];
            cv[c] = tgt[((size_t)b * 3 + c) * NN + m];
            Ss[c] += sv[c];
            Sc[c] += cv[c];
        }
#pragma unroll
        for (int c = 0; c < 3; ++c)
#pragma unroll
            for (int d = 0; d < 3; ++d)
                P[c * 3 + d] = fmaf(sv[c], cv[d], P[c * 3 + d]);
    }

    float vals[15];
#pragma unroll
    for (int i = 0; i < 9; ++i) vals[i] = P[i];
#pragma unroll
    for (int i = 0; i < 3; ++i) { vals[9 + i] = Ss[i]; vals[12 + i] = Sc[i]; }

    __shared__ float red[16][15];
    const int lane = tid & 63, wv = tid >> 6;
#pragma unroll
    for (int i = 0; i < 15; ++i) {
        float v = vals[i];
        for (int off = 32; off > 0; off >>= 1) v += __shfl_down(v, off, 64);
        if (lane == 0) red[wv][i] = v;
    }
    __syncthreads();

    if (tid == 0) {
        double tot[15];
        for (int i = 0; i < 15; ++i) {
            double s = 0.0;
            for (int wq = 0; wq < 16; ++wq) s += (double)red[wq][i];
            tot[i] = s;
        }
        double smean[3], cmean[3], H[3][3];
        for (int c = 0; c < 3; ++c) { smean[c] = tot[9 + c] / NN; cmean[c] = tot[12 + c] / NN; }
        for (int c = 0; c < 3; ++c)
            for (int d = 0; d < 3; ++d)
                H[c][d] = tot[c * 3 + d] - tot[9 + c] * tot[12 + d] / NN;

        double W[3][3], V[3][3];
        for (int i = 0; i < 3; ++i)
            for (int j = 0; j < 3; ++j) { W[i][j] = H[i][j]; V[i][j] = (i == j) ? 1.0 : 0.0; }
        for (int sweep = 0; sweep < 60; ++sweep) {
            double offsum = 0.0;
            for (int p = 0; p < 2; ++p)
                for (int q = p + 1; q < 3; ++q) {
                    double al = 0, be = 0, ga = 0;
                    for (int r = 0; r < 3; ++r) {
                        al += W[r][p] * W[r][p];
                        be += W[r][q] * W[r][q];
                        ga += W[r][p] * W[r][q];
                    }
                    offsum += fabs(ga);
                    if (fabs(ga) <= 1e-15 * sqrt(al * be)) continue;
                    double zeta = (be - al) / (2.0 * ga);
                    double t = copysign(1.0, zeta) / (fabs(zeta) + sqrt(1.0 + zeta * zeta));
                    double c = 1.0 / sqrt(1.0 + t * t), s = c * t;
                    for (int r = 0; r < 3; ++r) {
                        double wp = W[r][p], wq = W[r][q];
                        W[r][p] = c * wp - s * wq;
                        W[r][q] = s * wp + c * wq;
                        double vp = V[r][p], vq = V[r][q];
                        V[r][p] = c * vp - s * vq;
                        V[r][q] = s * vp + c * vq;
                    }
                }
            if (offsum < 1e-13) break;
        }
        double S[3];
        for (int i = 0; i < 3; ++i)
            S[i] = sqrt(W[0][i] * W[0][i] + W[1][i] * W[1][i] + W[2][i] * W[2][i]);
        for (int i = 0; i < 2; ++i) {
            int mx = i;
            for (int j = i + 1; j < 3; ++j) if (S[j] > S[mx]) mx = j;
            if (mx != i) {
                double tS = S[i]; S[i] = S[mx]; S[mx] = tS;
                for (int r = 0; r < 3; ++r) {
                    double tw = W[r][i]; W[r][i] = W[r][mx]; W[r][mx] = tw;
                    double tv = V[r][i]; V[r][i] = V[r][mx]; V[r][mx] = tv;
                }
            }
        }
        double U[3][3];
        for (int i = 0; i < 3; ++i) {
            if (S[i] > 1e-12 * S[0] && S[i] > 0.0) {
                for (int r = 0; r < 3; ++r) U[r][i] = W[r][i] / S[i];
            } else {
                double ux = U[1][0] * U[2][1] - U[2][0] * U[1][1];
                double uy = U[2][0] * U[0][1] - U[0][0] * U[2][1];
                double uz = U[0][0] * U[1][1] - U[1][0] * U[0][1];
                double nr = sqrt(ux * ux + uy * uy + uz * uz);
                if (nr < 1e-30) { ux = 1.0; uy = 0.0; uz = 0.0; nr = 1.0; }
                U[0][i] = ux / nr; U[1][i] = uy / nr; U[2][i] = uz / nr;
            }
        }
        double r_[3][3];
        for (int i = 0; i < 3; ++i)
            for (int j = 0; j < 3; ++j)
                r_[i][j] = V[i][0] * U[j][0] + V[i][1] * U[j][1] + V[i][2] * U[j][2];
        double det = det3(r_);
        double R[3][3];
        for (int i = 0; i < 3; ++i)
            for (int j = 0; j < 3; ++j)
                R[i][j] = V[i][0] * U[j][0] + V[i][1] * U[j][1] + det * V[i][2] * U[j][2];
        double t_[3];
        for (int i = 0; i < 3; ++i)
            t_[i] = -(R[i][0] * smean[0] + R[i][1] * smean[1] + R[i][2] * smean[2]) + cmean[i];

        for (int i = 0; i < 3; ++i)
            for (int j = 0; j < 3; ++j)
                out[b * 9 + i * 3 + j] = (float)R[i][j];
        for (int i = 0; i < 3; ++i) out[NB * 9 + b * 3 + i] = (float)t_[i];
    }
}

// ---------- launcher ----------
extern "C" void kernel_launch(void* const* d_in, const int* in_sizes, int n_in,
                              void* d_out, int out_size, void* d_ws, size_t ws_size,
                              hipStream_t stream)
{
    const float* srcE = (const float*)d_in[0];
    const float* tgtE = (const float*)d_in[1];
    const float* src  = (const float*)d_in[2];
    const float* tgt  = (const float*)d_in[3];
    const float* temp = (const float*)d_in[4];
    const float* gum  = (const float*)d_in[5];
    float* out = (float*)d_out;
    unsigned long long* best = (unsigned long long*)d_ws;

    (void)hipMemsetAsync(best, 0, (size_t)NB * NN * sizeof(unsigned long long), stream);

    const size_t PLANE = (size_t)NB * NN * NC;                 // u16 elements per plane
    const size_t NEED  = 131072 + 4 * PLANE * sizeof(unsigned short);  // 128KB + 64MB
    if (ws_size >= NEED) {
        unsigned short* hiA = (unsigned short*)((char*)d_ws + 131072);
        unsigned short* loA = hiA + PLANE;
        unsigned short* hiB = loA + PLANE;
        unsigned short* loB = hiB + PLANE;
        prepack<<<dim3(1024, 2), 256, 0, stream>>>(srcE, tgtE, hiA, loA, hiB, loB);
        scores_argmax_256b<<<512, 1024, 0, stream>>>(hiA, loA, hiB, loB, gum, best);
    } else {
        scores_argmax<<<2048, 256, 0, stream>>>(srcE, tgtE, gum, temp, best);
    }
    assemble<<<NB, 1024, 0, stream>>>(src, tgt, best, out);
}